// Round 2
// baseline (4709.266 us; speedup 1.0000x reference)
//
#include <hip/hip_runtime.h>
#include <math.h>

// Problem constants (match reference)
#define BB 4
#define TT 2048
#define RTOT 8192      // B*T
#define DD 1024
#define HH 4
#define DKC 1024
#define DVC 2048
#define HKC 256
#define HVC 512
#define TILE_CV 32     // conv time-tile (rows) for in-place conv

typedef unsigned short u16;
typedef unsigned int u32;

__device__ __forceinline__ float bf2f(u16 u) {
    union { float f; u32 i; } c; c.i = ((u32)u) << 16; return c.f;
}
__device__ __forceinline__ u16 f2bf(float f) {
    union { float f; u32 i; } c; c.f = f;
    const u32 i = c.i;
    return (u16)((i + 0x7FFFu + ((i >> 16) & 1u)) >> 16);   // RNE; inputs finite
}
__device__ __forceinline__ float sigmoidf_(float x) { return 1.0f / (1.0f + expf(-x)); }

// ---------------- LayerNorm: fp32 x -> bf16 normed ----------------
__global__ __launch_bounds__(256) void ln_kernel(const float* __restrict__ x,
                                                 const float* __restrict__ w,
                                                 const float* __restrict__ b,
                                                 u16* __restrict__ out) {
    const int row = blockIdx.x;
    const int tid = threadIdx.x;
    const int lane = tid & 63, wave = tid >> 6;
    const float4 xv = *(const float4*)&x[(size_t)row * DD + tid * 4];
    float s = xv.x + xv.y + xv.z + xv.w;
    float sq = xv.x * xv.x + xv.y * xv.y + xv.z * xv.z + xv.w * xv.w;
    for (int m = 32; m >= 1; m >>= 1) {
        s += __shfl_xor(s, m, 64);
        sq += __shfl_xor(sq, m, 64);
    }
    __shared__ float s1[4], s2[4];
    if (lane == 0) { s1[wave] = s; s2[wave] = sq; }
    __syncthreads();
    const float tot = s1[0] + s1[1] + s1[2] + s1[3];
    const float totq = s2[0] + s2[1] + s2[2] + s2[3];
    const float mean = tot * (1.0f / DD);
    const float var = totq * (1.0f / DD) - mean * mean;
    const float rstd = rsqrtf(var + 1e-5f);
    const float4 wv = *(const float4*)&w[tid * 4];
    const float4 bv = *(const float4*)&b[tid * 4];
    ushort4 o;
    o.x = f2bf((xv.x - mean) * rstd * wv.x + bv.x);
    o.y = f2bf((xv.y - mean) * rstd * wv.y + bv.y);
    o.z = f2bf((xv.z - mean) * rstd * wv.z + bv.z);
    o.w = f2bf((xv.w - mean) * rstd * wv.w + bv.w);
    *(ushort4*)&out[(size_t)row * DD + tid * 4] = o;
}

// ---------------- tiled GEMM: C[M,N] = A_bf16[M,K] @ B_f32[K,N]  ----------------
// OUTMODE 0: bf16 output, no residual.  OUTMODE 1: fp32 output + fp32 residual.
// 128x128 tile, BK=8, 256 threads, 8x8 per thread; fp32 accumulate.
template <int OUTMODE>
__global__ __launch_bounds__(256) void gemm_ab(const u16* __restrict__ A,
                                               const float* __restrict__ Bw,
                                               void* __restrict__ Cv,
                                               int M, int N, int K,
                                               const float* __restrict__ Res) {
    __shared__ float As[8][128];
    __shared__ float Bs[8][128];
    const int tid = threadIdx.x;
    const int tx = tid & 15, ty = tid >> 4;
    const int bn = blockIdx.x, bm = blockIdx.y;
    float acc[8][8] = {};
    const int ar = tid >> 1, ac = (tid & 1) * 4;
    const int br = tid >> 5, bc = (tid & 31) * 4;
    const u16* Aptr = A + (size_t)(bm * 128 + ar) * K + ac;
    const float* Bptr = Bw + (size_t)br * N + bn * 128 + bc;
    for (int k0 = 0; k0 < K; k0 += 8) {
        const ushort4 a4 = *(const ushort4*)(Aptr + k0);
        const float4 b4 = *(const float4*)(Bptr + (size_t)k0 * N);
        As[ac + 0][ar] = bf2f(a4.x); As[ac + 1][ar] = bf2f(a4.y);
        As[ac + 2][ar] = bf2f(a4.z); As[ac + 3][ar] = bf2f(a4.w);
        *(float4*)&Bs[br][bc] = b4;
        __syncthreads();
#pragma unroll
        for (int kk = 0; kk < 8; ++kk) {
            const float4 alo = *(const float4*)&As[kk][ty * 4];
            const float4 ahi = *(const float4*)&As[kk][64 + ty * 4];
            const float4 blo = *(const float4*)&Bs[kk][tx * 4];
            const float4 bhi = *(const float4*)&Bs[kk][64 + tx * 4];
            const float av[8] = {alo.x, alo.y, alo.z, alo.w, ahi.x, ahi.y, ahi.z, ahi.w};
            const float bv[8] = {blo.x, blo.y, blo.z, blo.w, bhi.x, bhi.y, bhi.z, bhi.w};
#pragma unroll
            for (int i = 0; i < 8; ++i)
#pragma unroll
                for (int j = 0; j < 8; ++j)
                    acc[i][j] = fmaf(av[i], bv[j], acc[i][j]);
        }
        __syncthreads();
    }
#pragma unroll
    for (int ii = 0; ii < 8; ++ii) {
        const int r = bm * 128 + ((ii < 4) ? (ty * 4 + ii) : (64 + ty * 4 + ii - 4));
        const size_t rowoff = (size_t)r * N + bn * 128;
        const int c0 = tx * 4, c1 = 64 + tx * 4;
        if (OUTMODE == 0) {
            u16* C = (u16*)Cv;
            ushort4 s0, s1;
            s0.x = f2bf(acc[ii][0]); s0.y = f2bf(acc[ii][1]);
            s0.z = f2bf(acc[ii][2]); s0.w = f2bf(acc[ii][3]);
            s1.x = f2bf(acc[ii][4]); s1.y = f2bf(acc[ii][5]);
            s1.z = f2bf(acc[ii][6]); s1.w = f2bf(acc[ii][7]);
            *(ushort4*)&C[rowoff + c0] = s0;
            *(ushort4*)&C[rowoff + c1] = s1;
        } else {
            float* C = (float*)Cv;
            float4 v0 = make_float4(acc[ii][0], acc[ii][1], acc[ii][2], acc[ii][3]);
            float4 v1 = make_float4(acc[ii][4], acc[ii][5], acc[ii][6], acc[ii][7]);
            const float4 r0 = *(const float4*)&Res[rowoff + c0];
            const float4 r1 = *(const float4*)&Res[rowoff + c1];
            v0.x += r0.x; v0.y += r0.y; v0.z += r0.z; v0.w += r0.w;
            v1.x += r1.x; v1.y += r1.y; v1.z += r1.z; v1.w += r1.w;
            *(float4*)&C[rowoff + c0] = v0;
            *(float4*)&C[rowoff + c1] = v1;
        }
    }
}

// ---------------- beta = sigmoid(n@Wb), g = -exp(A)*softplus(n@Wa+dt) ----------------
// Recomputes LN from fp32 x internally (keeps the gating path free of bf16 noise).
__global__ __launch_bounds__(256) void smallproj_kernel(const float* __restrict__ x,
                                                        const float* __restrict__ lnw,
                                                        const float* __restrict__ lnb,
                                                        const float* __restrict__ Wb,
                                                        const float* __restrict__ Wa,
                                                        const float* __restrict__ A_log,
                                                        const float* __restrict__ dt_bias,
                                                        float* __restrict__ beta,
                                                        float* __restrict__ gdec) {
    const int row = blockIdx.x;
    const int tid = threadIdx.x;
    const int lane = tid & 63, wave = tid >> 6;
    const float4 xv = *(const float4*)&x[(size_t)row * DD + tid * 4];
    float s = xv.x + xv.y + xv.z + xv.w;
    float sq = xv.x * xv.x + xv.y * xv.y + xv.z * xv.z + xv.w * xv.w;
    for (int m = 32; m >= 1; m >>= 1) {
        s += __shfl_xor(s, m, 64);
        sq += __shfl_xor(sq, m, 64);
    }
    __shared__ float s1[4], s2[4];
    if (lane == 0) { s1[wave] = s; s2[wave] = sq; }
    __syncthreads();
    const float mean = (s1[0] + s1[1] + s1[2] + s1[3]) * (1.0f / DD);
    const float var = (s2[0] + s2[1] + s2[2] + s2[3]) * (1.0f / DD) - mean * mean;
    const float rstd = rsqrtf(var + 1e-5f);
    const float4 wv = *(const float4*)&lnw[tid * 4];
    const float4 bv = *(const float4*)&lnb[tid * 4];
    float nv[4];
    nv[0] = (xv.x - mean) * rstd * wv.x + bv.x;
    nv[1] = (xv.y - mean) * rstd * wv.y + bv.y;
    nv[2] = (xv.z - mean) * rstd * wv.z + bv.z;
    nv[3] = (xv.w - mean) * rstd * wv.w + bv.w;
    float acc[8] = {};
#pragma unroll
    for (int j = 0; j < 4; ++j) {
        const int kk = tid * 4 + j;
        const float4 wb = ((const float4*)Wb)[kk];
        const float4 wa = ((const float4*)Wa)[kk];
        acc[0] += nv[j] * wb.x; acc[1] += nv[j] * wb.y; acc[2] += nv[j] * wb.z; acc[3] += nv[j] * wb.w;
        acc[4] += nv[j] * wa.x; acc[5] += nv[j] * wa.y; acc[6] += nv[j] * wa.z; acc[7] += nv[j] * wa.w;
    }
#pragma unroll
    for (int i = 0; i < 8; ++i)
        for (int m = 32; m >= 1; m >>= 1) acc[i] += __shfl_xor(acc[i], m, 64);
    __shared__ float sred[4][8];
    if (lane == 0)
#pragma unroll
        for (int i = 0; i < 8; ++i) sred[wave][i] = acc[i];
    __syncthreads();
    if (tid < 8) {
        const float sv = sred[0][tid] + sred[1][tid] + sred[2][tid] + sred[3][tid];
        if (tid < 4) {
            beta[(size_t)row * HH + tid] = 1.0f / (1.0f + expf(-sv));
        } else {
            const int h = tid - 4;
            const float z = sv + dt_bias[h];
            const float sp = (z > 20.0f) ? z : log1pf(expf(z));
            gdec[(size_t)row * HH + h] = -expf(A_log[h]) * sp;
        }
    }
}

// ---------------- halo save: copy rows {r0-1, r0-2, r0-3} per tile (pre-conv values) ----------------
__global__ __launch_bounds__(256) void halo_save(const u16* __restrict__ P,
                                                 u16* __restrict__ halo, int C) {
    const int tt = blockIdx.x;
    const int r0 = tt * TILE_CV;
    const int t0 = r0 & (TT - 1);
    const int n4 = (3 * C) >> 2;
    for (int idx = threadIdx.x; idx < n4; idx += 256) {
        const int flat = idx * 4;
        const int j = flat / C;        // 0..2  -> row r0-1-j
        const int c = flat - j * C;
        ushort4 vv;
        if (t0 == 0) { vv.x = vv.y = vv.z = vv.w = 0; }
        else vv = *(const ushort4*)&P[(size_t)(r0 - 1 - j) * C + c];
        *(ushort4*)&halo[(size_t)(tt * 3 + j) * C + c] = vv;
    }
}

// ---------------- in-place depthwise causal conv (K=4) + SiLU, bf16 ----------------
// One block owns a 32-row time tile x 1024-channel strip; ascending t with rolling regs.
__global__ __launch_bounds__(256) void conv_inplace(u16* __restrict__ P,
                                                    const float* __restrict__ w,
                                                    const u16* __restrict__ halo, int C) {
    const int tt = blockIdx.y;
    const int r0 = tt * TILE_CV;
    const int c0 = blockIdx.x * 1024 + threadIdx.x * 4;
    float wt[4][4];
#pragma unroll
    for (int j = 0; j < 4; ++j)
#pragma unroll
        for (int i = 0; i < 4; ++i) wt[j][i] = w[(c0 + j) * 4 + i];
    float xm1[4], xm2[4], xm3[4];
    {
        const ushort4 h0 = *(const ushort4*)&halo[(size_t)(tt * 3 + 0) * C + c0]; // r0-1
        const ushort4 h1 = *(const ushort4*)&halo[(size_t)(tt * 3 + 1) * C + c0]; // r0-2
        const ushort4 h2 = *(const ushort4*)&halo[(size_t)(tt * 3 + 2) * C + c0]; // r0-3
        xm1[0] = bf2f(h0.x); xm1[1] = bf2f(h0.y); xm1[2] = bf2f(h0.z); xm1[3] = bf2f(h0.w);
        xm2[0] = bf2f(h1.x); xm2[1] = bf2f(h1.y); xm2[2] = bf2f(h1.z); xm2[3] = bf2f(h1.w);
        xm3[0] = bf2f(h2.x); xm3[1] = bf2f(h2.y); xm3[2] = bf2f(h2.z); xm3[3] = bf2f(h2.w);
    }
    for (int t = 0; t < TILE_CV; ++t) {
        u16* rowp = P + (size_t)(r0 + t) * C + c0;
        const ushort4 cv = *(const ushort4*)rowp;
        float cur[4] = {bf2f(cv.x), bf2f(cv.y), bf2f(cv.z), bf2f(cv.w)};
        ushort4 ov;
        u16* op = (u16*)&ov;
#pragma unroll
        for (int j = 0; j < 4; ++j) {
            const float y = xm3[j] * wt[j][0] + xm2[j] * wt[j][1] + xm1[j] * wt[j][2] + cur[j] * wt[j][3];
            op[j] = f2bf(y * sigmoidf_(y));
        }
        *(ushort4*)rowp = ov;
#pragma unroll
        for (int j = 0; j < 4; ++j) { xm3[j] = xm2[j]; xm2[j] = xm1[j]; xm1[j] = cur[j]; }
    }
}

// ---------------- per-head l2norm for q (x 1/16) and k, in place (bf16) ----------------
__global__ __launch_bounds__(256) void normqk_kernel(u16* __restrict__ q, u16* __restrict__ k) {
    const int row = blockIdx.x;
    const int tid = threadIdx.x;
    const int h = tid >> 6, lane = tid & 63;
    const size_t base = (size_t)row * DKC + h * HKC + lane * 4;
    const ushort4 q4 = *(ushort4*)&q[base];
    const ushort4 k4 = *(ushort4*)&k[base];
    float qv[4] = {bf2f(q4.x), bf2f(q4.y), bf2f(q4.z), bf2f(q4.w)};
    float kv[4] = {bf2f(k4.x), bf2f(k4.y), bf2f(k4.z), bf2f(k4.w)};
    float sq = qv[0] * qv[0] + qv[1] * qv[1] + qv[2] * qv[2] + qv[3] * qv[3];
    float sk = kv[0] * kv[0] + kv[1] * kv[1] + kv[2] * kv[2] + kv[3] * kv[3];
    for (int m = 32; m >= 1; m >>= 1) {
        sq += __shfl_xor(sq, m, 64);
        sk += __shfl_xor(sk, m, 64);
    }
    const float qs = rsqrtf(sq + 1e-6f) * 0.0625f;   // * HK^-0.5
    const float ks = rsqrtf(sk + 1e-6f);
    ushort4 qo, ko;
    qo.x = f2bf(qv[0] * qs); qo.y = f2bf(qv[1] * qs); qo.z = f2bf(qv[2] * qs); qo.w = f2bf(qv[3] * qs);
    ko.x = f2bf(kv[0] * ks); ko.y = f2bf(kv[1] * ks); ko.z = f2bf(kv[2] * ks); ko.w = f2bf(kv[3] * ks);
    *(ushort4*)&q[base] = qo;
    *(ushort4*)&k[base] = ko;
}

// ---------------- gated delta rule scan, column-parallel (bf16 io, fp32 state) ----------------
// block: 4 waves; each wave owns one state column (HK=256 rows, 4/lane).
// blocks: B*H*(HV/4) = 2048. LDS-stage k/q (8 steps, fp32) shared by the 4 waves.
__global__ __launch_bounds__(256) void scan_kernel(const u16* __restrict__ qb,
                                                   const u16* __restrict__ kb,
                                                   const u16* __restrict__ vb,
                                                   const float* __restrict__ gdec,
                                                   const float* __restrict__ beta,
                                                   u16* __restrict__ ob) {
    const int bid = blockIdx.x;
    const int cg = bid & 127;
    const int h = (bid >> 7) & 3;
    const int b = bid >> 9;
    const int wave = threadIdx.x >> 6, lane = threadIdx.x & 63;
    const int col = cg * 4 + wave;
    __shared__ float k_s[8][256];
    __shared__ float q_s[8][256];
    __shared__ float v_s[8][4];
    __shared__ float g_s[8], b_s[8];
    float4 S = {0.f, 0.f, 0.f, 0.f};
    const int rowbase = b * TT;
    for (int t0 = 0; t0 < TT; t0 += 8) {
#pragma unroll
        for (int r = 0; r < 2; ++r) {
            const int f = (threadIdx.x + r * 256) * 4;
            const int s = f >> 8, c = f & 255;
            const size_t off = (size_t)(rowbase + t0 + s) * DKC + h * HKC + c;
            const ushort4 kk4 = *(const ushort4*)&kb[off];
            const ushort4 qq4 = *(const ushort4*)&qb[off];
            k_s[s][c + 0] = bf2f(kk4.x); k_s[s][c + 1] = bf2f(kk4.y);
            k_s[s][c + 2] = bf2f(kk4.z); k_s[s][c + 3] = bf2f(kk4.w);
            q_s[s][c + 0] = bf2f(qq4.x); q_s[s][c + 1] = bf2f(qq4.y);
            q_s[s][c + 2] = bf2f(qq4.z); q_s[s][c + 3] = bf2f(qq4.w);
        }
        if (threadIdx.x < 32) {
            const int s = threadIdx.x >> 2, cc = threadIdx.x & 3;
            v_s[s][cc] = bf2f(vb[(size_t)(rowbase + t0 + s) * DVC + h * HVC + cg * 4 + cc]);
        } else if (threadIdx.x < 40) {
            g_s[threadIdx.x - 32] = gdec[(size_t)(rowbase + t0 + threadIdx.x - 32) * HH + h];
        } else if (threadIdx.x < 48) {
            b_s[threadIdx.x - 40] = beta[(size_t)(rowbase + t0 + threadIdx.x - 40) * HH + h];
        }
        __syncthreads();
#pragma unroll
        for (int s = 0; s < 8; ++s) {
            const float4 kv = *(const float4*)&k_s[s][lane * 4];
            const float4 qv = *(const float4*)&q_s[s][lane * 4];
            const float alpha = expf(g_s[s]);
            float d = kv.x * S.x + kv.y * S.y + kv.z * S.z + kv.w * S.w;
            for (int m = 32; m >= 1; m >>= 1) d += __shfl_xor(d, m, 64);
            const float veff = (v_s[s][wave] - alpha * d) * b_s[s];
            S.x = alpha * S.x + kv.x * veff;
            S.y = alpha * S.y + kv.y * veff;
            S.z = alpha * S.z + kv.z * veff;
            S.w = alpha * S.w + kv.w * veff;
            float ov = qv.x * S.x + qv.y * S.y + qv.z * S.z + qv.w * S.w;
            for (int m = 32; m >= 1; m >>= 1) ov += __shfl_xor(ov, m, 64);
            if (lane == 0) ob[(size_t)(rowbase + t0 + s) * DVC + h * HVC + col] = f2bf(ov);
        }
        __syncthreads();
    }
}

// ---------------- RMSNorm (per head over HV=512) * norm_w * silu-gate, in place (bf16) ----------------
__global__ __launch_bounds__(256) void gate_kernel(u16* __restrict__ o,
                                                   const u16* __restrict__ pg,
                                                   const float* __restrict__ norm_w) {
    const int row = blockIdx.x;
    const int tid = threadIdx.x;
    const int h = tid >> 6, lane = tid & 63;
    const size_t base = (size_t)row * DVC + h * HVC + lane * 4;
    const ushort4 a4 = *(ushort4*)&o[base];
    const ushort4 b4 = *(ushort4*)&o[base + 256];
    float o1[4] = {bf2f(a4.x), bf2f(a4.y), bf2f(a4.z), bf2f(a4.w)};
    float o2[4] = {bf2f(b4.x), bf2f(b4.y), bf2f(b4.z), bf2f(b4.w)};
    float ss = 0.f;
#pragma unroll
    for (int j = 0; j < 4; ++j) ss += o1[j] * o1[j] + o2[j] * o2[j];
    for (int m = 32; m >= 1; m >>= 1) ss += __shfl_xor(ss, m, 64);
    const float rms = rsqrtf(ss * (1.0f / HVC) + 1e-5f);
    const float4 nw1 = *(const float4*)&norm_w[lane * 4];
    const float4 nw2 = *(const float4*)&norm_w[256 + lane * 4];
    const ushort4 g4a = *(const ushort4*)&pg[base];
    const ushort4 g4b = *(const ushort4*)&pg[base + 256];
    const float g1[4] = {bf2f(g4a.x), bf2f(g4a.y), bf2f(g4a.z), bf2f(g4a.w)};
    const float g2[4] = {bf2f(g4b.x), bf2f(g4b.y), bf2f(g4b.z), bf2f(g4b.w)};
    const float n1[4] = {nw1.x, nw1.y, nw1.z, nw1.w};
    const float n2[4] = {nw2.x, nw2.y, nw2.z, nw2.w};
    ushort4 r1, r2;
    u16* p1 = (u16*)&r1; u16* p2 = (u16*)&r2;
#pragma unroll
    for (int j = 0; j < 4; ++j) {
        p1[j] = f2bf(o1[j] * rms * n1[j] * g1[j] * sigmoidf_(g1[j]));
        p2[j] = f2bf(o2[j] * rms * n2[j] * g2[j] * sigmoidf_(g2[j]));
    }
    *(ushort4*)&o[base] = r1;
    *(ushort4*)&o[base + 256] = r2;
}

extern "C" void kernel_launch(void* const* d_in, const int* in_sizes, int n_in,
                              void* d_out, int out_size, void* d_ws, size_t ws_size,
                              hipStream_t stream) {
    const float* x       = (const float*)d_in[0];
    const float* ln_w    = (const float*)d_in[1];
    const float* ln_b    = (const float*)d_in[2];
    const float* Wq      = (const float*)d_in[3];
    const float* Wk      = (const float*)d_in[4];
    const float* Wv      = (const float*)d_in[5];
    const float* conv_q  = (const float*)d_in[6];
    const float* conv_k  = (const float*)d_in[7];
    const float* conv_v  = (const float*)d_in[8];
    const float* Wb      = (const float*)d_in[9];
    const float* Wa      = (const float*)d_in[10];
    const float* A_log   = (const float*)d_in[11];
    const float* dt_bias = (const float*)d_in[12];
    const float* Wg      = (const float*)d_in[13];
    const float* norm_w  = (const float*)d_in[14];
    const float* Wo      = (const float*)d_in[15];
    float* out = (float*)d_out;

    // Workspace layout (bytes): total 116 MB
    char* ws = (char*)d_ws;
    u16* normed = (u16*)(ws);                          // [0,16) MB   bf16 [8192,1024]
    u16* q      = (u16*)(ws + (16ull << 20));          // [16,32) MB  bf16 [8192,1024]
    u16* k      = (u16*)(ws + (32ull << 20));          // [32,48) MB  bf16 [8192,1024]
    u16* v      = (u16*)(ws + (48ull << 20));          // [48,80) MB  bf16 [8192,2048]
    u16* o      = (u16*)(ws + (80ull << 20));          // [80,112) MB bf16 [8192,2048]
    u16* pg     = q;                                   // reuse q+k (32MB) after scan
    float* beta = (float*)(ws + (112ull << 20));            // 128 KB
    float* gdec = (float*)(ws + (112ull << 20) + 131072);   // 128 KB
    u16* halo   = (u16*)(ws + (113ull << 20));         // 3 MB (256 tiles x 3 rows x 2048ch)

    ln_kernel<<<RTOT, 256, 0, stream>>>(x, ln_w, ln_b, normed);

    gemm_ab<0><<<dim3(DKC / 128, RTOT / 128), 256, 0, stream>>>(normed, Wq, q, RTOT, DKC, DD, nullptr);
    gemm_ab<0><<<dim3(DKC / 128, RTOT / 128), 256, 0, stream>>>(normed, Wk, k, RTOT, DKC, DD, nullptr);
    gemm_ab<0><<<dim3(DVC / 128, RTOT / 128), 256, 0, stream>>>(normed, Wv, v, RTOT, DVC, DD, nullptr);
    smallproj_kernel<<<RTOT, 256, 0, stream>>>(x, ln_w, ln_b, Wb, Wa, A_log, dt_bias, beta, gdec);

    halo_save<<<RTOT / TILE_CV, 256, 0, stream>>>(q, halo, DKC);
    conv_inplace<<<dim3(1, RTOT / TILE_CV), 256, 0, stream>>>(q, conv_q, halo, DKC);
    halo_save<<<RTOT / TILE_CV, 256, 0, stream>>>(k, halo, DKC);
    conv_inplace<<<dim3(1, RTOT / TILE_CV), 256, 0, stream>>>(k, conv_k, halo, DKC);
    halo_save<<<RTOT / TILE_CV, 256, 0, stream>>>(v, halo, DVC);
    conv_inplace<<<dim3(2, RTOT / TILE_CV), 256, 0, stream>>>(v, conv_v, halo, DVC);

    normqk_kernel<<<RTOT, 256, 0, stream>>>(q, k);

    scan_kernel<<<BB * HH * (HVC / 4), 256, 0, stream>>>(q, k, v, gdec, beta, o);

    // q,k dead now -> their 32MB holds the output-gate projection
    gemm_ab<0><<<dim3(DVC / 128, RTOT / 128), 256, 0, stream>>>(normed, Wg, pg, RTOT, DVC, DD, nullptr);

    gate_kernel<<<RTOT, 256, 0, stream>>>(o, pg, norm_w);

    gemm_ab<1><<<dim3(DD / 128, RTOT / 128), 256, 0, stream>>>(o, Wo, out, RTOT, DD, DVC, x);
}

// Round 3
// 2005.810 us; speedup vs baseline: 2.3478x; 2.3478x over previous
//
#include <hip/hip_runtime.h>
#include <math.h>

// Problem constants (match reference)
#define BB 4
#define TT 2048
#define RTOT 8192      // B*T
#define DD 1024
#define HH 4
#define DKC 1024
#define DVC 2048
#define HKC 256
#define HVC 512
#define NC 32          // chunks per sequence (T/64)
#define TILE_CV 32     // conv time-tile (rows) for in-place conv

typedef unsigned short u16;
typedef unsigned int u32;
typedef short bf8v __attribute__((ext_vector_type(8)));   // 8 bf16 in 4 VGPRs
typedef float f32x4 __attribute__((ext_vector_type(4)));

__device__ __forceinline__ float bf2f(u16 u) {
    union { float f; u32 i; } c; c.i = ((u32)u) << 16; return c.f;
}
__device__ __forceinline__ u16 f2bf(float f) {
    union { float f; u32 i; } c; c.f = f;
    const u32 i = c.i;
    return (u16)((i + 0x7FFFu + ((i >> 16) & 1u)) >> 16);   // RNE; inputs finite
}
__device__ __forceinline__ float sigmoidf_(float x) { return 1.0f / (1.0f + expf(-x)); }
__device__ __forceinline__ f32x4 mfma16(bf8v a, bf8v b, f32x4 c) {
    return __builtin_amdgcn_mfma_f32_16x16x32_bf16(a, b, c, 0, 0, 0);
}

// ---------------- LayerNorm: fp32 x -> bf16 normed ----------------
__global__ __launch_bounds__(256) void ln_kernel(const float* __restrict__ x,
                                                 const float* __restrict__ w,
                                                 const float* __restrict__ b,
                                                 u16* __restrict__ out) {
    const int row = blockIdx.x;
    const int tid = threadIdx.x;
    const int lane = tid & 63, wave = tid >> 6;
    const float4 xv = *(const float4*)&x[(size_t)row * DD + tid * 4];
    float s = xv.x + xv.y + xv.z + xv.w;
    float sq = xv.x * xv.x + xv.y * xv.y + xv.z * xv.z + xv.w * xv.w;
    for (int m = 32; m >= 1; m >>= 1) {
        s += __shfl_xor(s, m, 64);
        sq += __shfl_xor(sq, m, 64);
    }
    __shared__ float s1[4], s2[4];
    if (lane == 0) { s1[wave] = s; s2[wave] = sq; }
    __syncthreads();
    const float tot = s1[0] + s1[1] + s1[2] + s1[3];
    const float totq = s2[0] + s2[1] + s2[2] + s2[3];
    const float mean = tot * (1.0f / DD);
    const float var = totq * (1.0f / DD) - mean * mean;
    const float rstd = rsqrtf(var + 1e-5f);
    const float4 wv = *(const float4*)&w[tid * 4];
    const float4 bv = *(const float4*)&b[tid * 4];
    ushort4 o;
    o.x = f2bf((xv.x - mean) * rstd * wv.x + bv.x);
    o.y = f2bf((xv.y - mean) * rstd * wv.y + bv.y);
    o.z = f2bf((xv.z - mean) * rstd * wv.z + bv.z);
    o.w = f2bf((xv.w - mean) * rstd * wv.w + bv.w);
    *(ushort4*)&out[(size_t)row * DD + tid * 4] = o;
}

// ---------------- tiled GEMM: C[M,N] = A_bf16[M,K] @ B_f32[K,N]  ----------------
template <int OUTMODE>
__global__ __launch_bounds__(256) void gemm_ab(const u16* __restrict__ A,
                                               const float* __restrict__ Bw,
                                               void* __restrict__ Cv,
                                               int M, int N, int K,
                                               const float* __restrict__ Res) {
    __shared__ float As[8][128];
    __shared__ float Bs[8][128];
    const int tid = threadIdx.x;
    const int tx = tid & 15, ty = tid >> 4;
    const int bn = blockIdx.x, bm = blockIdx.y;
    float acc[8][8] = {};
    const int ar = tid >> 1, ac = (tid & 1) * 4;
    const int br = tid >> 5, bc = (tid & 31) * 4;
    const u16* Aptr = A + (size_t)(bm * 128 + ar) * K + ac;
    const float* Bptr = Bw + (size_t)br * N + bn * 128 + bc;
    for (int k0 = 0; k0 < K; k0 += 8) {
        const ushort4 a4 = *(const ushort4*)(Aptr + k0);
        const float4 b4 = *(const float4*)(Bptr + (size_t)k0 * N);
        As[ac + 0][ar] = bf2f(a4.x); As[ac + 1][ar] = bf2f(a4.y);
        As[ac + 2][ar] = bf2f(a4.z); As[ac + 3][ar] = bf2f(a4.w);
        *(float4*)&Bs[br][bc] = b4;
        __syncthreads();
#pragma unroll
        for (int kk = 0; kk < 8; ++kk) {
            const float4 alo = *(const float4*)&As[kk][ty * 4];
            const float4 ahi = *(const float4*)&As[kk][64 + ty * 4];
            const float4 blo = *(const float4*)&Bs[kk][tx * 4];
            const float4 bhi = *(const float4*)&Bs[kk][64 + tx * 4];
            const float av[8] = {alo.x, alo.y, alo.z, alo.w, ahi.x, ahi.y, ahi.z, ahi.w};
            const float bv[8] = {blo.x, blo.y, blo.z, blo.w, bhi.x, bhi.y, bhi.z, bhi.w};
#pragma unroll
            for (int i = 0; i < 8; ++i)
#pragma unroll
                for (int j = 0; j < 8; ++j)
                    acc[i][j] = fmaf(av[i], bv[j], acc[i][j]);
        }
        __syncthreads();
    }
#pragma unroll
    for (int ii = 0; ii < 8; ++ii) {
        const int r = bm * 128 + ((ii < 4) ? (ty * 4 + ii) : (64 + ty * 4 + ii - 4));
        const size_t rowoff = (size_t)r * N + bn * 128;
        const int c0 = tx * 4, c1 = 64 + tx * 4;
        if (OUTMODE == 0) {
            u16* C = (u16*)Cv;
            ushort4 s0, s1;
            s0.x = f2bf(acc[ii][0]); s0.y = f2bf(acc[ii][1]);
            s0.z = f2bf(acc[ii][2]); s0.w = f2bf(acc[ii][3]);
            s1.x = f2bf(acc[ii][4]); s1.y = f2bf(acc[ii][5]);
            s1.z = f2bf(acc[ii][6]); s1.w = f2bf(acc[ii][7]);
            *(ushort4*)&C[rowoff + c0] = s0;
            *(ushort4*)&C[rowoff + c1] = s1;
        } else {
            float* C = (float*)Cv;
            float4 v0 = make_float4(acc[ii][0], acc[ii][1], acc[ii][2], acc[ii][3]);
            float4 v1 = make_float4(acc[ii][4], acc[ii][5], acc[ii][6], acc[ii][7]);
            const float4 r0 = *(const float4*)&Res[rowoff + c0];
            const float4 r1 = *(const float4*)&Res[rowoff + c1];
            v0.x += r0.x; v0.y += r0.y; v0.z += r0.z; v0.w += r0.w;
            v1.x += r1.x; v1.y += r1.y; v1.z += r1.z; v1.w += r1.w;
            *(float4*)&C[rowoff + c0] = v0;
            *(float4*)&C[rowoff + c1] = v1;
        }
    }
}

// ---------------- beta = sigmoid(n@Wb), g = -exp(A)*softplus(n@Wa+dt) ----------------
__global__ __launch_bounds__(256) void smallproj_kernel(const float* __restrict__ x,
                                                        const float* __restrict__ lnw,
                                                        const float* __restrict__ lnb,
                                                        const float* __restrict__ Wb,
                                                        const float* __restrict__ Wa,
                                                        const float* __restrict__ A_log,
                                                        const float* __restrict__ dt_bias,
                                                        float* __restrict__ beta,
                                                        float* __restrict__ gdec) {
    const int row = blockIdx.x;
    const int tid = threadIdx.x;
    const int lane = tid & 63, wave = tid >> 6;
    const float4 xv = *(const float4*)&x[(size_t)row * DD + tid * 4];
    float s = xv.x + xv.y + xv.z + xv.w;
    float sq = xv.x * xv.x + xv.y * xv.y + xv.z * xv.z + xv.w * xv.w;
    for (int m = 32; m >= 1; m >>= 1) {
        s += __shfl_xor(s, m, 64);
        sq += __shfl_xor(sq, m, 64);
    }
    __shared__ float s1[4], s2[4];
    if (lane == 0) { s1[wave] = s; s2[wave] = sq; }
    __syncthreads();
    const float mean = (s1[0] + s1[1] + s1[2] + s1[3]) * (1.0f / DD);
    const float var = (s2[0] + s2[1] + s2[2] + s2[3]) * (1.0f / DD) - mean * mean;
    const float rstd = rsqrtf(var + 1e-5f);
    const float4 wv = *(const float4*)&lnw[tid * 4];
    const float4 bv = *(const float4*)&lnb[tid * 4];
    float nv[4];
    nv[0] = (xv.x - mean) * rstd * wv.x + bv.x;
    nv[1] = (xv.y - mean) * rstd * wv.y + bv.y;
    nv[2] = (xv.z - mean) * rstd * wv.z + bv.z;
    nv[3] = (xv.w - mean) * rstd * wv.w + bv.w;
    float acc[8] = {};
#pragma unroll
    for (int j = 0; j < 4; ++j) {
        const int kk = tid * 4 + j;
        const float4 wb = ((const float4*)Wb)[kk];
        const float4 wa = ((const float4*)Wa)[kk];
        acc[0] += nv[j] * wb.x; acc[1] += nv[j] * wb.y; acc[2] += nv[j] * wb.z; acc[3] += nv[j] * wb.w;
        acc[4] += nv[j] * wa.x; acc[5] += nv[j] * wa.y; acc[6] += nv[j] * wa.z; acc[7] += nv[j] * wa.w;
    }
#pragma unroll
    for (int i = 0; i < 8; ++i)
        for (int m = 32; m >= 1; m >>= 1) acc[i] += __shfl_xor(acc[i], m, 64);
    __shared__ float sred[4][8];
    if (lane == 0)
#pragma unroll
        for (int i = 0; i < 8; ++i) sred[wave][i] = acc[i];
    __syncthreads();
    if (tid < 8) {
        const float sv = sred[0][tid] + sred[1][tid] + sred[2][tid] + sred[3][tid];
        if (tid < 4) {
            beta[(size_t)row * HH + tid] = 1.0f / (1.0f + expf(-sv));
        } else {
            const int h = tid - 4;
            const float z = sv + dt_bias[h];
            const float sp = (z > 20.0f) ? z : log1pf(expf(z));
            gdec[(size_t)row * HH + h] = -expf(A_log[h]) * sp;
        }
    }
}

// ---------------- halo save (pre-conv boundary rows per tile) ----------------
__global__ __launch_bounds__(256) void halo_save(const u16* __restrict__ P,
                                                 u16* __restrict__ halo, int C) {
    const int tt = blockIdx.x;
    const int r0 = tt * TILE_CV;
    const int t0 = r0 & (TT - 1);
    const int n4 = (3 * C) >> 2;
    for (int idx = threadIdx.x; idx < n4; idx += 256) {
        const int flat = idx * 4;
        const int j = flat / C;
        const int c = flat - j * C;
        ushort4 vv;
        if (t0 == 0) { vv.x = vv.y = vv.z = vv.w = 0; }
        else vv = *(const ushort4*)&P[(size_t)(r0 - 1 - j) * C + c];
        *(ushort4*)&halo[(size_t)(tt * 3 + j) * C + c] = vv;
    }
}

// ---------------- in-place depthwise causal conv (K=4) + SiLU, bf16 ----------------
__global__ __launch_bounds__(256) void conv_inplace(u16* __restrict__ P,
                                                    const float* __restrict__ w,
                                                    const u16* __restrict__ halo, int C) {
    const int tt = blockIdx.y;
    const int r0 = tt * TILE_CV;
    const int c0 = blockIdx.x * 1024 + threadIdx.x * 4;
    float wt[4][4];
#pragma unroll
    for (int j = 0; j < 4; ++j)
#pragma unroll
        for (int i = 0; i < 4; ++i) wt[j][i] = w[(c0 + j) * 4 + i];
    float xm1[4], xm2[4], xm3[4];
    {
        const ushort4 h0 = *(const ushort4*)&halo[(size_t)(tt * 3 + 0) * C + c0];
        const ushort4 h1 = *(const ushort4*)&halo[(size_t)(tt * 3 + 1) * C + c0];
        const ushort4 h2 = *(const ushort4*)&halo[(size_t)(tt * 3 + 2) * C + c0];
        xm1[0] = bf2f(h0.x); xm1[1] = bf2f(h0.y); xm1[2] = bf2f(h0.z); xm1[3] = bf2f(h0.w);
        xm2[0] = bf2f(h1.x); xm2[1] = bf2f(h1.y); xm2[2] = bf2f(h1.z); xm2[3] = bf2f(h1.w);
        xm3[0] = bf2f(h2.x); xm3[1] = bf2f(h2.y); xm3[2] = bf2f(h2.z); xm3[3] = bf2f(h2.w);
    }
    for (int t = 0; t < TILE_CV; ++t) {
        u16* rowp = P + (size_t)(r0 + t) * C + c0;
        const ushort4 cv = *(const ushort4*)rowp;
        float cur[4] = {bf2f(cv.x), bf2f(cv.y), bf2f(cv.z), bf2f(cv.w)};
        ushort4 ov;
        u16* op = (u16*)&ov;
#pragma unroll
        for (int j = 0; j < 4; ++j) {
            const float y = xm3[j] * wt[j][0] + xm2[j] * wt[j][1] + xm1[j] * wt[j][2] + cur[j] * wt[j][3];
            op[j] = f2bf(y * sigmoidf_(y));
        }
        *(ushort4*)rowp = ov;
#pragma unroll
        for (int j = 0; j < 4; ++j) { xm3[j] = xm2[j]; xm2[j] = xm1[j]; xm1[j] = cur[j]; }
    }
}

// ---------------- per-head l2norm for q (x 1/16) and k, in place (bf16) ----------------
__global__ __launch_bounds__(256) void normqk_kernel(u16* __restrict__ q, u16* __restrict__ k) {
    const int row = blockIdx.x;
    const int tid = threadIdx.x;
    const int h = tid >> 6, lane = tid & 63;
    const size_t base = (size_t)row * DKC + h * HKC + lane * 4;
    const ushort4 q4 = *(ushort4*)&q[base];
    const ushort4 k4 = *(ushort4*)&k[base];
    float qv[4] = {bf2f(q4.x), bf2f(q4.y), bf2f(q4.z), bf2f(q4.w)};
    float kv[4] = {bf2f(k4.x), bf2f(k4.y), bf2f(k4.z), bf2f(k4.w)};
    float sq = qv[0]*qv[0] + qv[1]*qv[1] + qv[2]*qv[2] + qv[3]*qv[3];
    float sk = kv[0]*kv[0] + kv[1]*kv[1] + kv[2]*kv[2] + kv[3]*kv[3];
    for (int m = 32; m >= 1; m >>= 1) {
        sq += __shfl_xor(sq, m, 64);
        sk += __shfl_xor(sk, m, 64);
    }
    const float qs = rsqrtf(sq + 1e-6f) * 0.0625f;
    const float ks = rsqrtf(sk + 1e-6f);
    ushort4 qo, ko;
    qo.x = f2bf(qv[0]*qs); qo.y = f2bf(qv[1]*qs); qo.z = f2bf(qv[2]*qs); qo.w = f2bf(qv[3]*qs);
    ko.x = f2bf(kv[0]*ks); ko.y = f2bf(kv[1]*ks); ko.z = f2bf(kv[2]*ks); ko.w = f2bf(kv[3]*ks);
    *(ushort4*)&q[base] = qo;
    *(ushort4*)&k[base] = ko;
}

// ---------------- P1a: per-chunk T, M=(I+T)^-1, P (decayed QK^T), gc ----------------
// grid = B*H*NC = 512 blocks, 256 threads. MFMA frags read from global directly.
__global__ __launch_bounds__(256) void p1a_kernel(const u16* __restrict__ qg,
                                                  const u16* __restrict__ kg,
                                                  const float* __restrict__ gdec,
                                                  const float* __restrict__ beta,
                                                  u16* __restrict__ Mg,
                                                  u16* __restrict__ Pg,
                                                  float* __restrict__ gcg) {
    __shared__ float T[64][68];
    __shared__ float Mm[64][68];
    __shared__ float gcs[64], bars[64];
    const int CI = blockIdx.x;
    const int c = CI & 31, h = (CI >> 5) & 3, b = CI >> 7;
    const int tid = threadIdx.x, lane = tid & 63, wave = tid >> 6;
    const int quad = lane >> 4, l15 = lane & 15;
    const int rowbase = b * TT + c * 64;
    if (wave == 0) {
        float g = gdec[(size_t)(rowbase + lane) * HH + h];
        for (int d = 1; d < 64; d <<= 1) { float o2 = __shfl_up(g, d, 64); if (lane >= d) g += o2; }
        gcs[lane] = g;
        bars[lane] = beta[(size_t)(rowbase + lane) * HH + h];
        gcg[CI * 64 + lane] = g;
    }
    __syncthreads();
    const int t0 = wave * 16;
    f32x4 kk[4], qk[4];
#pragma unroll
    for (int st = 0; st < 4; ++st) { kk[st] = (f32x4){0,0,0,0}; qk[st] = (f32x4){0,0,0,0}; }
    const size_t arow = (size_t)(rowbase + t0 + l15) * DKC + h * HKC + quad * 8;
    for (int ks = 0; ks < 8; ++ks) {
        const bf8v ak = *(const bf8v*)(kg + arow + ks * 32);
        const bf8v aq = *(const bf8v*)(qg + arow + ks * 32);
#pragma unroll
        for (int st = 0; st < 4; ++st) {
            const size_t brow = (size_t)(rowbase + st * 16 + l15) * DKC + h * HKC + quad * 8 + ks * 32;
            const bf8v bk = *(const bf8v*)(kg + brow);
            kk[st] = mfma16(ak, bk, kk[st]);
            qk[st] = mfma16(aq, bk, qk[st]);
        }
    }
#pragma unroll
    for (int st = 0; st < 4; ++st)
#pragma unroll
        for (int i = 0; i < 4; ++i) {
            const int t = t0 + quad * 4 + i, s = st * 16 + l15;
            const float e = expf(gcs[t] - gcs[s]);   // <= 1, safe (log-domain diff)
            T[t][s] = (s < t) ? bars[t] * e * kk[st][i] : 0.f;
            Pg[(size_t)CI * 4096 + t * 64 + s] = f2bf((s <= t) ? e * qk[st][i] : 0.f);
        }
    __syncthreads();
    // forward substitution for M = (I+T)^{-1}: wave 0, lane = column j
    if (wave == 0) {
        const int j = lane;
        Mm[0][j] = (j == 0) ? 1.f : 0.f;
        for (int t = 1; t < 64; ++t) {
            float acc = 0.f;
            for (int s = 0; s < t; ++s) acc += T[t][s] * Mm[s][j];
            Mm[t][j] = ((t == j) ? 1.f : 0.f) - acc;
        }
    }
    __syncthreads();
    for (int idx = tid; idx < 4096; idx += 256)
        Mg[(size_t)CI * 4096 + idx] = f2bf(Mm[idx >> 6][idx & 63]);
}

// ---------------- P2: sequential inter-chunk recurrence, MFMA GEMMs ----------------
// grid = B*H*(HVC/32) = 256 blocks, 256 threads (4 waves). fp32 state in accs,
// bf16 shadow S_bT in LDS. Per chunk: u = bv - (bg k)@S ; veff = M@u ;
// o = P@veff + (g q)@S ; S = gC*S + K'^T@veff.
__global__ __launch_bounds__(256) void p2_kernel(const u16* __restrict__ qg,
                                                 const u16* __restrict__ kg,
                                                 const u16* __restrict__ vg,
                                                 const float* __restrict__ beta,
                                                 const float* __restrict__ gcg,
                                                 const u16* __restrict__ Mg,
                                                 const u16* __restrict__ Pg,
                                                 u16* __restrict__ og) {
    __shared__ u16 SbT[32][264];     // S^T bf16: [n][r], pad->2-way banks, 16B rows
    __shared__ u16 buf[18432];       // kA/qA view [64][264] ; kT view [256][72]
    __shared__ u16 tT[32][72];       // uT then veffT: [n][s]
    __shared__ float barr[64], negbg[64], gamt[64], gcdg[64];
    __shared__ float gCsh;
    const int bid = blockIdx.x;
    const int vs = bid & 15, h = (bid >> 4) & 3, b = bid >> 6;
    const int tid = threadIdx.x, lane = tid & 63, wave = tid >> 6;
    const int quad = lane >> 4, l15 = lane & 15;
    const int t0 = wave * 16;
    for (int i = tid; i < 32 * 264; i += 256) ((u16*)SbT)[i] = 0;
    f32x4 S[4][2];
#pragma unroll
    for (int a = 0; a < 4; ++a)
#pragma unroll
        for (int nb = 0; nb < 2; ++nb) S[a][nb] = (f32x4){0,0,0,0};

    const int srow = tid >> 2, scq = tid & 3;    // staging: row, col-quarter

    for (int c = 0; c < NC; ++c) {
        const int CI = (b * 4 + h) * NC + c;
        const int rowbase = b * TT + c * 64;
        __syncthreads();                         // SbT (prev chunk) visible; scal free
        if (wave == 0) {
            const float gc = gcg[CI * 64 + lane];
            const float gc63 = __shfl(gc, 63, 64);
            const float bt = beta[(size_t)(rowbase + lane) * HH + h];
            const float gt = expf(gc);
            barr[lane] = bt; gamt[lane] = gt;
            negbg[lane] = -bt * gt;
            gcdg[lane] = expf(gc63 - gc);
            if (lane == 0) gCsh = expf(gc63);
        }
        __syncthreads();                         // scalars ready
        {   // stage kA[t][r] = negbg[t]*k[t][r] into buf[t*264 + r]
            const float sc = negbg[srow];
            const u16* krow = kg + (size_t)(rowbase + srow) * DKC + h * HKC + scq * 64;
            u16* dst = buf + srow * 264 + scq * 64;
#pragma unroll
            for (int it = 0; it < 8; ++it) {
                const ushort4 a0 = *(const ushort4*)(krow + it * 8);
                const ushort4 a1 = *(const ushort4*)(krow + it * 8 + 4);
                ushort4 o0, o1;
                o0.x = f2bf(bf2f(a0.x)*sc); o0.y = f2bf(bf2f(a0.y)*sc);
                o0.z = f2bf(bf2f(a0.z)*sc); o0.w = f2bf(bf2f(a0.w)*sc);
                o1.x = f2bf(bf2f(a1.x)*sc); o1.y = f2bf(bf2f(a1.y)*sc);
                o1.z = f2bf(bf2f(a1.z)*sc); o1.w = f2bf(bf2f(a1.w)*sc);
                *(ushort4*)(dst + it * 8) = o0;
                *(ushort4*)(dst + it * 8 + 4) = o1;
            }
        }
        __syncthreads();                         // kA staged
        // ---- step1: u = beta*v + kA@Sb ----
        f32x4 uacc[2];
#pragma unroll
        for (int nb = 0; nb < 2; ++nb) {
            f32x4 ci;
#pragma unroll
            for (int i = 0; i < 4; ++i) {
                const int t = t0 + quad * 4 + i;
                ci[i] = barr[t] * bf2f(vg[(size_t)(rowbase + t) * DVC + h * HVC + vs * 32 + nb * 16 + l15]);
            }
            uacc[nb] = ci;
        }
        for (int ks = 0; ks < 8; ++ks) {
            const bf8v af = *(const bf8v*)(buf + (t0 + l15) * 264 + ks * 32 + quad * 8);
#pragma unroll
            for (int nb = 0; nb < 2; ++nb) {
                const bf8v bf_ = *(const bf8v*)(&SbT[nb * 16 + l15][ks * 32 + quad * 8]);
                uacc[nb] = mfma16(af, bf_, uacc[nb]);
            }
        }
#pragma unroll
        for (int nb = 0; nb < 2; ++nb) {         // write uT[n][t]
            ushort4 p;
            p.x = f2bf(uacc[nb][0]); p.y = f2bf(uacc[nb][1]);
            p.z = f2bf(uacc[nb][2]); p.w = f2bf(uacc[nb][3]);
            *(ushort4*)(&tT[nb * 16 + l15][t0 + quad * 4]) = p;
        }
        __syncthreads();                         // uT ready
        // ---- step2: veff = M@u ----
        f32x4 vacc[2] = {(f32x4){0,0,0,0}, (f32x4){0,0,0,0}};
        for (int ks = 0; ks < 2; ++ks) {
            const bf8v am = *(const bf8v*)(Mg + (size_t)CI * 4096 + (t0 + l15) * 64 + ks * 32 + quad * 8);
#pragma unroll
            for (int nb = 0; nb < 2; ++nb) {
                const bf8v bu = *(const bf8v*)(&tT[nb * 16 + l15][ks * 32 + quad * 8]);
                vacc[nb] = mfma16(am, bu, vacc[nb]);
            }
        }
        {   // stage qA[t][r] = gamt[t]*q[t][r] into buf (kA consumed by step1)
            const float sc = gamt[srow];
            const u16* qrow = qg + (size_t)(rowbase + srow) * DKC + h * HKC + scq * 64;
            u16* dst = buf + srow * 264 + scq * 64;
#pragma unroll
            for (int it = 0; it < 8; ++it) {
                const ushort4 a0 = *(const ushort4*)(qrow + it * 8);
                const ushort4 a1 = *(const ushort4*)(qrow + it * 8 + 4);
                ushort4 o0, o1;
                o0.x = f2bf(bf2f(a0.x)*sc); o0.y = f2bf(bf2f(a0.y)*sc);
                o0.z = f2bf(bf2f(a0.z)*sc); o0.w = f2bf(bf2f(a0.w)*sc);
                o1.x = f2bf(bf2f(a1.x)*sc); o1.y = f2bf(bf2f(a1.y)*sc);
                o1.z = f2bf(bf2f(a1.z)*sc); o1.w = f2bf(bf2f(a1.w)*sc);
                *(ushort4*)(dst + it * 8) = o0;
                *(ushort4*)(dst + it * 8 + 4) = o1;
            }
        }
        __syncthreads();                         // all uT reads done; qA staged
#pragma unroll
        for (int nb = 0; nb < 2; ++nb) {         // write veffT over uT
            ushort4 p;
            p.x = f2bf(vacc[nb][0]); p.y = f2bf(vacc[nb][1]);
            p.z = f2bf(vacc[nb][2]); p.w = f2bf(vacc[nb][3]);
            *(ushort4*)(&tT[nb * 16 + l15][t0 + quad * 4]) = p;
        }
        __syncthreads();                         // veffT ready
        // ---- step3: o = P@veff + qA@Sb ----
        f32x4 oacc[2] = {(f32x4){0,0,0,0}, (f32x4){0,0,0,0}};
        for (int ks = 0; ks < 2; ++ks) {
            const bf8v ap = *(const bf8v*)(Pg + (size_t)CI * 4096 + (t0 + l15) * 64 + ks * 32 + quad * 8);
#pragma unroll
            for (int nb = 0; nb < 2; ++nb) {
                const bf8v bv_ = *(const bf8v*)(&tT[nb * 16 + l15][ks * 32 + quad * 8]);
                oacc[nb] = mfma16(ap, bv_, oacc[nb]);
            }
        }
        for (int ks = 0; ks < 8; ++ks) {
            const bf8v af = *(const bf8v*)(buf + (t0 + l15) * 264 + ks * 32 + quad * 8);
#pragma unroll
            for (int nb = 0; nb < 2; ++nb) {
                const bf8v bs = *(const bf8v*)(&SbT[nb * 16 + l15][ks * 32 + quad * 8]);
                oacc[nb] = mfma16(af, bs, oacc[nb]);
            }
        }
#pragma unroll
        for (int nb = 0; nb < 2; ++nb)
#pragma unroll
            for (int i = 0; i < 4; ++i) {
                const int t = t0 + quad * 4 + i;
                og[((size_t)(b * 4 + h) * TT + c * 64 + t) * HVC + vs * 32 + nb * 16 + l15] = f2bf(oacc[nb][i]);
            }
        __syncthreads();                         // qA consumed
        {   // stage kT[r][s] = gcdg[s]*k[s][r] into buf[r*72 + s]
            const float sc = gcdg[srow];
            const u16* krow = kg + (size_t)(rowbase + srow) * DKC + h * HKC + scq * 64;
#pragma unroll
            for (int it = 0; it < 8; ++it) {
                const ushort4 a0 = *(const ushort4*)(krow + it * 8);
                const ushort4 a1 = *(const ushort4*)(krow + it * 8 + 4);
                const int cbase = scq * 64 + it * 8;
                buf[(cbase + 0) * 72 + srow] = f2bf(bf2f(a0.x)*sc);
                buf[(cbase + 1) * 72 + srow] = f2bf(bf2f(a0.y)*sc);
                buf[(cbase + 2) * 72 + srow] = f2bf(bf2f(a0.z)*sc);
                buf[(cbase + 3) * 72 + srow] = f2bf(bf2f(a0.w)*sc);
                buf[(cbase + 4) * 72 + srow] = f2bf(bf2f(a1.x)*sc);
                buf[(cbase + 5) * 72 + srow] = f2bf(bf2f(a1.y)*sc);
                buf[(cbase + 6) * 72 + srow] = f2bf(bf2f(a1.z)*sc);
                buf[(cbase + 7) * 72 + srow] = f2bf(bf2f(a1.w)*sc);
            }
        }
        __syncthreads();                         // kT ready
        // ---- step4: S = gC*S + kT@veff ; refresh SbT ----
        const float gC = gCsh;
#pragma unroll
        for (int a = 0; a < 4; ++a) {
            const int r0 = (wave * 4 + a) * 16;
#pragma unroll
            for (int nb = 0; nb < 2; ++nb) {
                f32x4 acc = S[a][nb] * gC;
                for (int ks = 0; ks < 2; ++ks) {
                    const bf8v akt = *(const bf8v*)(buf + (r0 + l15) * 72 + ks * 32 + quad * 8);
                    const bf8v bv_ = *(const bf8v*)(&tT[nb * 16 + l15][ks * 32 + quad * 8]);
                    acc = mfma16(akt, bv_, acc);
                }
                S[a][nb] = acc;
                ushort4 p;
                p.x = f2bf(acc[0]); p.y = f2bf(acc[1]);
                p.z = f2bf(acc[2]); p.w = f2bf(acc[3]);
                *(ushort4*)(&SbT[nb * 16 + l15][r0 + quad * 4]) = p;
            }
        }
    }
}

// ---------------- RMSNorm + silu-gate; reads o (chunk layout), writes pg in place ----------------
__global__ __launch_bounds__(256) void gate_kernel(const u16* __restrict__ o,
                                                   u16* __restrict__ pg,
                                                   const float* __restrict__ norm_w) {
    const int row = blockIdx.x;
    const int b = row >> 11, t = row & 2047;
    const int tid = threadIdx.x;
    const int h = tid >> 6, lane = tid & 63;
    const size_t obase = ((size_t)(b * 4 + h) * TT + t) * HVC + lane * 4;
    const size_t pbase = (size_t)row * DVC + h * HVC + lane * 4;
    const ushort4 a4 = *(const ushort4*)&o[obase];
    const ushort4 b4 = *(const ushort4*)&o[obase + 256];
    float o1[4] = {bf2f(a4.x), bf2f(a4.y), bf2f(a4.z), bf2f(a4.w)};
    float o2[4] = {bf2f(b4.x), bf2f(b4.y), bf2f(b4.z), bf2f(b4.w)};
    float ss = 0.f;
#pragma unroll
    for (int j = 0; j < 4; ++j) ss += o1[j]*o1[j] + o2[j]*o2[j];
    for (int m = 32; m >= 1; m >>= 1) ss += __shfl_xor(ss, m, 64);
    const float rms = rsqrtf(ss * (1.0f / HVC) + 1e-5f);
    const float4 nw1 = *(const float4*)&norm_w[lane * 4];
    const float4 nw2 = *(const float4*)&norm_w[256 + lane * 4];
    const ushort4 g4a = *(const ushort4*)&pg[pbase];
    const ushort4 g4b = *(const ushort4*)&pg[pbase + 256];
    const float g1[4] = {bf2f(g4a.x), bf2f(g4a.y), bf2f(g4a.z), bf2f(g4a.w)};
    const float g2[4] = {bf2f(g4b.x), bf2f(g4b.y), bf2f(g4b.z), bf2f(g4b.w)};
    const float n1[4] = {nw1.x, nw1.y, nw1.z, nw1.w};
    const float n2[4] = {nw2.x, nw2.y, nw2.z, nw2.w};
    ushort4 r1, r2;
    u16* p1 = (u16*)&r1; u16* p2 = (u16*)&r2;
#pragma unroll
    for (int j = 0; j < 4; ++j) {
        p1[j] = f2bf(o1[j] * rms * n1[j] * g1[j] * sigmoidf_(g1[j]));
        p2[j] = f2bf(o2[j] * rms * n2[j] * g2[j] * sigmoidf_(g2[j]));
    }
    *(ushort4*)&pg[pbase] = r1;
    *(ushort4*)&pg[pbase + 256] = r2;
}

extern "C" void kernel_launch(void* const* d_in, const int* in_sizes, int n_in,
                              void* d_out, int out_size, void* d_ws, size_t ws_size,
                              hipStream_t stream) {
    const float* x       = (const float*)d_in[0];
    const float* ln_w    = (const float*)d_in[1];
    const float* ln_b    = (const float*)d_in[2];
    const float* Wq      = (const float*)d_in[3];
    const float* Wk      = (const float*)d_in[4];
    const float* Wv      = (const float*)d_in[5];
    const float* conv_q  = (const float*)d_in[6];
    const float* conv_k  = (const float*)d_in[7];
    const float* conv_v  = (const float*)d_in[8];
    const float* Wb      = (const float*)d_in[9];
    const float* Wa      = (const float*)d_in[10];
    const float* A_log   = (const float*)d_in[11];
    const float* dt_bias = (const float*)d_in[12];
    const float* Wg      = (const float*)d_in[13];
    const float* norm_w  = (const float*)d_in[14];
    const float* Wo      = (const float*)d_in[15];
    float* out = (float*)d_out;

    // Workspace layout: ~124 MB
    char* ws = (char*)d_ws;
    u16* normed = (u16*)(ws);                           // 16MB [0,16)
    u16* q      = (u16*)(ws + (16ull << 20));           // 16MB [16,32)
    u16* k      = (u16*)(ws + (32ull << 20));           // 16MB [32,48)
    u16* v      = (u16*)(ws + (48ull << 20));           // 32MB [48,80)
    u16* o      = (u16*)(ws + (80ull << 20));           // 32MB [80,112) chunk layout [B,H,T,HV]
    float* beta = (float*)(ws + (112ull << 20));              // 128KB
    float* gdec = (float*)(ws + (112ull << 20) + (128u<<10)); // 128KB
    float* gcg  = (float*)(ws + (112ull << 20) + (256u<<10)); // 128KB
    u16* halo   = (u16*)(ws + (113ull << 20));          // 3MB
    u16* Mg     = (u16*)(ws + (116ull << 20));          // 4MB
    u16* Pg     = (u16*)(ws + (120ull << 20));          // 4MB
    u16* pg     = q;                                    // 32MB (q+k region) after p2

    ln_kernel<<<RTOT, 256, 0, stream>>>(x, ln_w, ln_b, normed);

    gemm_ab<0><<<dim3(DKC / 128, RTOT / 128), 256, 0, stream>>>(normed, Wq, q, RTOT, DKC, DD, nullptr);
    gemm_ab<0><<<dim3(DKC / 128, RTOT / 128), 256, 0, stream>>>(normed, Wk, k, RTOT, DKC, DD, nullptr);
    gemm_ab<0><<<dim3(DVC / 128, RTOT / 128), 256, 0, stream>>>(normed, Wv, v, RTOT, DVC, DD, nullptr);
    smallproj_kernel<<<RTOT, 256, 0, stream>>>(x, ln_w, ln_b, Wb, Wa, A_log, dt_bias, beta, gdec);

    halo_save<<<RTOT / TILE_CV, 256, 0, stream>>>(q, halo, DKC);
    conv_inplace<<<dim3(1, RTOT / TILE_CV), 256, 0, stream>>>(q, conv_q, halo, DKC);
    halo_save<<<RTOT / TILE_CV, 256, 0, stream>>>(k, halo, DKC);
    conv_inplace<<<dim3(1, RTOT / TILE_CV), 256, 0, stream>>>(k, conv_k, halo, DKC);
    halo_save<<<RTOT / TILE_CV, 256, 0, stream>>>(v, halo, DVC);
    conv_inplace<<<dim3(2, RTOT / TILE_CV), 256, 0, stream>>>(v, conv_v, halo, DVC);

    normqk_kernel<<<RTOT, 256, 0, stream>>>(q, k);

    p1a_kernel<<<BB * HH * NC, 256, 0, stream>>>(q, k, gdec, beta, Mg, Pg, gcg);
    p2_kernel<<<BB * HH * (HVC / 32), 256, 0, stream>>>(q, k, v, beta, gcg, Mg, Pg, o);

    // q,k dead now -> their 32MB holds the output-gate projection
    gemm_ab<0><<<dim3(DVC / 128, RTOT / 128), 256, 0, stream>>>(normed, Wg, pg, RTOT, DVC, DD, nullptr);

    gate_kernel<<<RTOT, 256, 0, stream>>>(o, pg, norm_w);

    gemm_ab<1><<<dim3(DD / 128, RTOT / 128), 256, 0, stream>>>(pg, Wo, out, RTOT, DD, DVC, x);
}

// Round 4
// 792.509 us; speedup vs baseline: 5.9422x; 2.5310x over previous
//
#include <hip/hip_runtime.h>
#include <math.h>

// Problem constants (match reference)
#define BB 4
#define TT 2048
#define RTOT 8192      // B*T
#define DD 1024
#define HH 4
#define DKC 1024
#define DVC 2048
#define HKC 256
#define HVC 512
#define NC 32          // chunks per sequence (T/64)
#define TILE_CV 32     // conv time-tile (rows) for in-place conv

typedef unsigned short u16;
typedef unsigned int u32;
typedef short bf8v __attribute__((ext_vector_type(8)));   // 8 bf16 in 4 VGPRs
typedef float f32x4 __attribute__((ext_vector_type(4)));

__device__ __forceinline__ float bf2f(u16 u) {
    union { float f; u32 i; } c; c.i = ((u32)u) << 16; return c.f;
}
__device__ __forceinline__ u16 f2bf(float f) {
    union { float f; u32 i; } c; c.f = f;
    const u32 i = c.i;
    return (u16)((i + 0x7FFFu + ((i >> 16) & 1u)) >> 16);   // RNE; inputs finite
}
__device__ __forceinline__ float sigmoidf_(float x) { return 1.0f / (1.0f + expf(-x)); }
__device__ __forceinline__ f32x4 mfma16(bf8v a, bf8v b, f32x4 c) {
    return __builtin_amdgcn_mfma_f32_16x16x32_bf16(a, b, c, 0, 0, 0);
}

// ---------------- LayerNorm: fp32 x -> bf16 normed ----------------
__global__ __launch_bounds__(256) void ln_kernel(const float* __restrict__ x,
                                                 const float* __restrict__ w,
                                                 const float* __restrict__ b,
                                                 u16* __restrict__ out) {
    const int row = blockIdx.x;
    const int tid = threadIdx.x;
    const int lane = tid & 63, wave = tid >> 6;
    const float4 xv = *(const float4*)&x[(size_t)row * DD + tid * 4];
    float s = xv.x + xv.y + xv.z + xv.w;
    float sq = xv.x * xv.x + xv.y * xv.y + xv.z * xv.z + xv.w * xv.w;
    for (int m = 32; m >= 1; m >>= 1) {
        s += __shfl_xor(s, m, 64);
        sq += __shfl_xor(sq, m, 64);
    }
    __shared__ float s1[4], s2[4];
    if (lane == 0) { s1[wave] = s; s2[wave] = sq; }
    __syncthreads();
    const float tot = s1[0] + s1[1] + s1[2] + s1[3];
    const float totq = s2[0] + s2[1] + s2[2] + s2[3];
    const float mean = tot * (1.0f / DD);
    const float var = totq * (1.0f / DD) - mean * mean;
    const float rstd = rsqrtf(var + 1e-5f);
    const float4 wv = *(const float4*)&w[tid * 4];
    const float4 bv = *(const float4*)&b[tid * 4];
    ushort4 o;
    o.x = f2bf((xv.x - mean) * rstd * wv.x + bv.x);
    o.y = f2bf((xv.y - mean) * rstd * wv.y + bv.y);
    o.z = f2bf((xv.z - mean) * rstd * wv.z + bv.z);
    o.w = f2bf((xv.w - mean) * rstd * wv.w + bv.w);
    *(ushort4*)&out[(size_t)row * DD + tid * 4] = o;
}

// ---------------- weight transpose+convert: WT[n][k] = bf16(W[k][n]) ----------------
__global__ __launch_bounds__(256) void wconv_kernel(const float* __restrict__ W,
                                                    u16* __restrict__ WT, int K, int N) {
    __shared__ float tile[32][33];
    const int k0 = blockIdx.x * 32, n0 = blockIdx.y * 32;
    const int t = threadIdx.x;
    const int r = t >> 3, c4 = (t & 7) * 4;
    const float4 v = *(const float4*)&W[(size_t)(k0 + r) * N + n0 + c4];
    tile[r][c4 + 0] = v.x; tile[r][c4 + 1] = v.y;
    tile[r][c4 + 2] = v.z; tile[r][c4 + 3] = v.w;
    __syncthreads();
    ushort4 o;
    o.x = f2bf(tile[c4 + 0][r]); o.y = f2bf(tile[c4 + 1][r]);
    o.z = f2bf(tile[c4 + 2][r]); o.w = f2bf(tile[c4 + 3][r]);
    *(ushort4*)&WT[(size_t)(n0 + r) * K + k0 + c4] = o;
}

// ---------------- MFMA GEMM: C[M,N] = A_bf16[M,K] @ WT_bf16[N,K]^T ----------------
// 128x128 tile, BK=32, 4 waves (2x2), each wave 4x4 grid of 16x16x32 MFMAs.
// OUTMODE 0: bf16 out. OUTMODE 1: fp32 out + fp32 residual.
template <int OUTMODE>
__global__ __launch_bounds__(256, 2) void gemm_mfma(const u16* __restrict__ A,
                                                    const u16* __restrict__ BT,
                                                    void* __restrict__ Cv,
                                                    int M, int N, int K,
                                                    const float* __restrict__ Res) {
    __shared__ u16 As[128][40];   // stride 40 bf16 = 80B (16B-aligned rows)
    __shared__ u16 Bs[128][40];
    const int tid = threadIdx.x;
    const int wave = tid >> 6, lane = tid & 63;
    const int quad = lane >> 4, l15 = lane & 15;
    const int wr = wave >> 1, wc = wave & 1;
    const int bn = blockIdx.x, bm = blockIdx.y;
    const int srow = tid >> 1, sh = (tid & 1) * 16;
    const u16* Ap = A + (size_t)(bm * 128 + srow) * K + sh;
    const u16* Bp = BT + (size_t)(bn * 128 + srow) * K + sh;
    f32x4 acc[4][4];
#pragma unroll
    for (int i = 0; i < 4; ++i)
#pragma unroll
        for (int j = 0; j < 4; ++j) acc[i][j] = (f32x4){0.f, 0.f, 0.f, 0.f};

    for (int k0 = 0; k0 < K; k0 += 32) {
        const bf8v a0 = *(const bf8v*)(Ap + k0);
        const bf8v a1 = *(const bf8v*)(Ap + k0 + 8);
        const bf8v b0 = *(const bf8v*)(Bp + k0);
        const bf8v b1 = *(const bf8v*)(Bp + k0 + 8);
        __syncthreads();                       // prev-iter LDS reads done
        *(bf8v*)&As[srow][sh] = a0;
        *(bf8v*)&As[srow][sh + 8] = a1;
        *(bf8v*)&Bs[srow][sh] = b0;
        *(bf8v*)&Bs[srow][sh + 8] = b1;
        __syncthreads();                       // staged
        bf8v af[4], bfr[4];
#pragma unroll
        for (int i = 0; i < 4; ++i) af[i] = *(const bf8v*)&As[wr * 64 + i * 16 + l15][quad * 8];
#pragma unroll
        for (int j = 0; j < 4; ++j) bfr[j] = *(const bf8v*)&Bs[wc * 64 + j * 16 + l15][quad * 8];
#pragma unroll
        for (int i = 0; i < 4; ++i)
#pragma unroll
            for (int j = 0; j < 4; ++j)
                acc[i][j] = mfma16(af[i], bfr[j], acc[i][j]);
    }
#pragma unroll
    for (int i = 0; i < 4; ++i) {
        const int row = bm * 128 + wr * 64 + i * 16 + quad * 4;
#pragma unroll
        for (int j = 0; j < 4; ++j) {
            const int col = bn * 128 + wc * 64 + j * 16 + l15;
            if (OUTMODE == 0) {
                u16* C = (u16*)Cv;
#pragma unroll
                for (int r = 0; r < 4; ++r)
                    C[(size_t)(row + r) * N + col] = f2bf(acc[i][j][r]);
            } else {
                float* C = (float*)Cv;
#pragma unroll
                for (int r = 0; r < 4; ++r)
                    C[(size_t)(row + r) * N + col] = acc[i][j][r] + Res[(size_t)(row + r) * N + col];
            }
        }
    }
}

// ---------------- beta = sigmoid(n@Wb), g = -exp(A)*softplus(n@Wa+dt) ----------------
__global__ __launch_bounds__(256) void smallproj_kernel(const float* __restrict__ x,
                                                        const float* __restrict__ lnw,
                                                        const float* __restrict__ lnb,
                                                        const float* __restrict__ Wb,
                                                        const float* __restrict__ Wa,
                                                        const float* __restrict__ A_log,
                                                        const float* __restrict__ dt_bias,
                                                        float* __restrict__ beta,
                                                        float* __restrict__ gdec) {
    const int row = blockIdx.x;
    const int tid = threadIdx.x;
    const int lane = tid & 63, wave = tid >> 6;
    const float4 xv = *(const float4*)&x[(size_t)row * DD + tid * 4];
    float s = xv.x + xv.y + xv.z + xv.w;
    float sq = xv.x * xv.x + xv.y * xv.y + xv.z * xv.z + xv.w * xv.w;
    for (int m = 32; m >= 1; m >>= 1) {
        s += __shfl_xor(s, m, 64);
        sq += __shfl_xor(sq, m, 64);
    }
    __shared__ float s1[4], s2[4];
    if (lane == 0) { s1[wave] = s; s2[wave] = sq; }
    __syncthreads();
    const float mean = (s1[0] + s1[1] + s1[2] + s1[3]) * (1.0f / DD);
    const float var = (s2[0] + s2[1] + s2[2] + s2[3]) * (1.0f / DD) - mean * mean;
    const float rstd = rsqrtf(var + 1e-5f);
    const float4 wv = *(const float4*)&lnw[tid * 4];
    const float4 bv = *(const float4*)&lnb[tid * 4];
    float nv[4];
    nv[0] = (xv.x - mean) * rstd * wv.x + bv.x;
    nv[1] = (xv.y - mean) * rstd * wv.y + bv.y;
    nv[2] = (xv.z - mean) * rstd * wv.z + bv.z;
    nv[3] = (xv.w - mean) * rstd * wv.w + bv.w;
    float acc[8] = {};
#pragma unroll
    for (int j = 0; j < 4; ++j) {
        const int kk = tid * 4 + j;
        const float4 wb = ((const float4*)Wb)[kk];
        const float4 wa = ((const float4*)Wa)[kk];
        acc[0] += nv[j] * wb.x; acc[1] += nv[j] * wb.y; acc[2] += nv[j] * wb.z; acc[3] += nv[j] * wb.w;
        acc[4] += nv[j] * wa.x; acc[5] += nv[j] * wa.y; acc[6] += nv[j] * wa.z; acc[7] += nv[j] * wa.w;
    }
#pragma unroll
    for (int i = 0; i < 8; ++i)
        for (int m = 32; m >= 1; m >>= 1) acc[i] += __shfl_xor(acc[i], m, 64);
    __shared__ float sred[4][8];
    if (lane == 0)
#pragma unroll
        for (int i = 0; i < 8; ++i) sred[wave][i] = acc[i];
    __syncthreads();
    if (tid < 8) {
        const float sv = sred[0][tid] + sred[1][tid] + sred[2][tid] + sred[3][tid];
        if (tid < 4) {
            beta[(size_t)row * HH + tid] = 1.0f / (1.0f + expf(-sv));
        } else {
            const int h = tid - 4;
            const float z = sv + dt_bias[h];
            const float sp = (z > 20.0f) ? z : log1pf(expf(z));
            gdec[(size_t)row * HH + h] = -expf(A_log[h]) * sp;
        }
    }
}

// ---------------- halo save (pre-conv boundary rows per tile) ----------------
__global__ __launch_bounds__(256) void halo_save(const u16* __restrict__ P,
                                                 u16* __restrict__ halo, int C) {
    const int tt = blockIdx.x;
    const int r0 = tt * TILE_CV;
    const int t0 = r0 & (TT - 1);
    const int n4 = (3 * C) >> 2;
    for (int idx = threadIdx.x; idx < n4; idx += 256) {
        const int flat = idx * 4;
        const int j = flat / C;
        const int c = flat - j * C;
        ushort4 vv;
        if (t0 == 0) { vv.x = vv.y = vv.z = vv.w = 0; }
        else vv = *(const ushort4*)&P[(size_t)(r0 - 1 - j) * C + c];
        *(ushort4*)&halo[(size_t)(tt * 3 + j) * C + c] = vv;
    }
}

// ---------------- in-place depthwise causal conv (K=4) + SiLU, bf16 ----------------
__global__ __launch_bounds__(256) void conv_inplace(u16* __restrict__ P,
                                                    const float* __restrict__ w,
                                                    const u16* __restrict__ halo, int C) {
    const int tt = blockIdx.y;
    const int r0 = tt * TILE_CV;
    const int c0 = blockIdx.x * 1024 + threadIdx.x * 4;
    float wt[4][4];
#pragma unroll
    for (int j = 0; j < 4; ++j)
#pragma unroll
        for (int i = 0; i < 4; ++i) wt[j][i] = w[(c0 + j) * 4 + i];
    float xm1[4], xm2[4], xm3[4];
    {
        const ushort4 h0 = *(const ushort4*)&halo[(size_t)(tt * 3 + 0) * C + c0];
        const ushort4 h1 = *(const ushort4*)&halo[(size_t)(tt * 3 + 1) * C + c0];
        const ushort4 h2 = *(const ushort4*)&halo[(size_t)(tt * 3 + 2) * C + c0];
        xm1[0] = bf2f(h0.x); xm1[1] = bf2f(h0.y); xm1[2] = bf2f(h0.z); xm1[3] = bf2f(h0.w);
        xm2[0] = bf2f(h1.x); xm2[1] = bf2f(h1.y); xm2[2] = bf2f(h1.z); xm2[3] = bf2f(h1.w);
        xm3[0] = bf2f(h2.x); xm3[1] = bf2f(h2.y); xm3[2] = bf2f(h2.z); xm3[3] = bf2f(h2.w);
    }
    for (int t = 0; t < TILE_CV; ++t) {
        u16* rowp = P + (size_t)(r0 + t) * C + c0;
        const ushort4 cv = *(const ushort4*)rowp;
        float cur[4] = {bf2f(cv.x), bf2f(cv.y), bf2f(cv.z), bf2f(cv.w)};
        ushort4 ov;
        u16* op = (u16*)&ov;
#pragma unroll
        for (int j = 0; j < 4; ++j) {
            const float y = xm3[j] * wt[j][0] + xm2[j] * wt[j][1] + xm1[j] * wt[j][2] + cur[j] * wt[j][3];
            op[j] = f2bf(y * sigmoidf_(y));
        }
        *(ushort4*)rowp = ov;
#pragma unroll
        for (int j = 0; j < 4; ++j) { xm3[j] = xm2[j]; xm2[j] = xm1[j]; xm1[j] = cur[j]; }
    }
}

// ---------------- per-head l2norm for q (x 1/16) and k, in place (bf16) ----------------
__global__ __launch_bounds__(256) void normqk_kernel(u16* __restrict__ q, u16* __restrict__ k) {
    const int row = blockIdx.x;
    const int tid = threadIdx.x;
    const int h = tid >> 6, lane = tid & 63;
    const size_t base = (size_t)row * DKC + h * HKC + lane * 4;
    const ushort4 q4 = *(ushort4*)&q[base];
    const ushort4 k4 = *(ushort4*)&k[base];
    float qv[4] = {bf2f(q4.x), bf2f(q4.y), bf2f(q4.z), bf2f(q4.w)};
    float kv[4] = {bf2f(k4.x), bf2f(k4.y), bf2f(k4.z), bf2f(k4.w)};
    float sq = qv[0]*qv[0] + qv[1]*qv[1] + qv[2]*qv[2] + qv[3]*qv[3];
    float sk = kv[0]*kv[0] + kv[1]*kv[1] + kv[2]*kv[2] + kv[3]*kv[3];
    for (int m = 32; m >= 1; m >>= 1) {
        sq += __shfl_xor(sq, m, 64);
        sk += __shfl_xor(sk, m, 64);
    }
    const float qs = rsqrtf(sq + 1e-6f) * 0.0625f;
    const float ks = rsqrtf(sk + 1e-6f);
    ushort4 qo, ko;
    qo.x = f2bf(qv[0]*qs); qo.y = f2bf(qv[1]*qs); qo.z = f2bf(qv[2]*qs); qo.w = f2bf(qv[3]*qs);
    ko.x = f2bf(kv[0]*ks); ko.y = f2bf(kv[1]*ks); ko.z = f2bf(kv[2]*ks); ko.w = f2bf(kv[3]*ks);
    *(ushort4*)&q[base] = qo;
    *(ushort4*)&k[base] = ko;
}

// ---------------- P1a: per-chunk T, M=(I+T)^-1, P (decayed QK^T), gc ----------------
__global__ __launch_bounds__(256) void p1a_kernel(const u16* __restrict__ qg,
                                                  const u16* __restrict__ kg,
                                                  const float* __restrict__ gdec,
                                                  const float* __restrict__ beta,
                                                  u16* __restrict__ Mg,
                                                  u16* __restrict__ Pg,
                                                  float* __restrict__ gcg) {
    __shared__ float T[64][68];
    __shared__ float Mm[64][68];
    __shared__ float gcs[64], bars[64];
    const int CI = blockIdx.x;
    const int c = CI & 31, h = (CI >> 5) & 3, b = CI >> 7;
    const int tid = threadIdx.x, lane = tid & 63, wave = tid >> 6;
    const int quad = lane >> 4, l15 = lane & 15;
    const int rowbase = b * TT + c * 64;
    if (wave == 0) {
        float g = gdec[(size_t)(rowbase + lane) * HH + h];
        for (int d = 1; d < 64; d <<= 1) { float o2 = __shfl_up(g, d, 64); if (lane >= d) g += o2; }
        gcs[lane] = g;
        bars[lane] = beta[(size_t)(rowbase + lane) * HH + h];
        gcg[CI * 64 + lane] = g;
    }
    __syncthreads();
    const int t0 = wave * 16;
    f32x4 kk[4], qk[4];
#pragma unroll
    for (int st = 0; st < 4; ++st) { kk[st] = (f32x4){0,0,0,0}; qk[st] = (f32x4){0,0,0,0}; }
    const size_t arow = (size_t)(rowbase + t0 + l15) * DKC + h * HKC + quad * 8;
    for (int ks = 0; ks < 8; ++ks) {
        const bf8v ak = *(const bf8v*)(kg + arow + ks * 32);
        const bf8v aq = *(const bf8v*)(qg + arow + ks * 32);
#pragma unroll
        for (int st = 0; st < 4; ++st) {
            const size_t brow = (size_t)(rowbase + st * 16 + l15) * DKC + h * HKC + quad * 8 + ks * 32;
            const bf8v bk = *(const bf8v*)(kg + brow);
            kk[st] = mfma16(ak, bk, kk[st]);
            qk[st] = mfma16(aq, bk, qk[st]);
        }
    }
#pragma unroll
    for (int st = 0; st < 4; ++st)
#pragma unroll
        for (int i = 0; i < 4; ++i) {
            const int t = t0 + quad * 4 + i, s = st * 16 + l15;
            const float e = expf(gcs[t] - gcs[s]);
            T[t][s] = (s < t) ? bars[t] * e * kk[st][i] : 0.f;
            Pg[(size_t)CI * 4096 + t * 64 + s] = f2bf((s <= t) ? e * qk[st][i] : 0.f);
        }
    __syncthreads();
    if (wave == 0) {
        const int j = lane;
        Mm[0][j] = (j == 0) ? 1.f : 0.f;
        for (int t = 1; t < 64; ++t) {
            float acc = 0.f;
            for (int s = 0; s < t; ++s) acc += T[t][s] * Mm[s][j];
            Mm[t][j] = ((t == j) ? 1.f : 0.f) - acc;
        }
    }
    __syncthreads();
    for (int idx = tid; idx < 4096; idx += 256)
        Mg[(size_t)CI * 4096 + idx] = f2bf(Mm[idx >> 6][idx & 63]);
}

// ---------------- P2: sequential inter-chunk recurrence, MFMA GEMMs ----------------
__global__ __launch_bounds__(256) void p2_kernel(const u16* __restrict__ qg,
                                                 const u16* __restrict__ kg,
                                                 const u16* __restrict__ vg,
                                                 const float* __restrict__ beta,
                                                 const float* __restrict__ gcg,
                                                 const u16* __restrict__ Mg,
                                                 const u16* __restrict__ Pg,
                                                 u16* __restrict__ og) {
    __shared__ u16 SbT[32][264];
    __shared__ u16 buf[18432];
    __shared__ u16 tT[32][72];
    __shared__ float barr[64], negbg[64], gamt[64], gcdg[64];
    __shared__ float gCsh;
    const int bid = blockIdx.x;
    const int vs = bid & 15, h = (bid >> 4) & 3, b = bid >> 6;
    const int tid = threadIdx.x, lane = tid & 63, wave = tid >> 6;
    const int quad = lane >> 4, l15 = lane & 15;
    const int t0 = wave * 16;
    for (int i = tid; i < 32 * 264; i += 256) ((u16*)SbT)[i] = 0;
    f32x4 S[4][2];
#pragma unroll
    for (int a = 0; a < 4; ++a)
#pragma unroll
        for (int nb = 0; nb < 2; ++nb) S[a][nb] = (f32x4){0,0,0,0};

    const int srow = tid >> 2, scq = tid & 3;

    for (int c = 0; c < NC; ++c) {
        const int CI = (b * 4 + h) * NC + c;
        const int rowbase = b * TT + c * 64;
        __syncthreads();
        if (wave == 0) {
            const float gc = gcg[CI * 64 + lane];
            const float gc63 = __shfl(gc, 63, 64);
            const float bt = beta[(size_t)(rowbase + lane) * HH + h];
            const float gt = expf(gc);
            barr[lane] = bt; gamt[lane] = gt;
            negbg[lane] = -bt * gt;
            gcdg[lane] = expf(gc63 - gc);
            if (lane == 0) gCsh = expf(gc63);
        }
        __syncthreads();
        {
            const float sc = negbg[srow];
            const u16* krow = kg + (size_t)(rowbase + srow) * DKC + h * HKC + scq * 64;
            u16* dst = buf + srow * 264 + scq * 64;
#pragma unroll
            for (int it = 0; it < 8; ++it) {
                const ushort4 a0 = *(const ushort4*)(krow + it * 8);
                const ushort4 a1 = *(const ushort4*)(krow + it * 8 + 4);
                ushort4 o0, o1;
                o0.x = f2bf(bf2f(a0.x)*sc); o0.y = f2bf(bf2f(a0.y)*sc);
                o0.z = f2bf(bf2f(a0.z)*sc); o0.w = f2bf(bf2f(a0.w)*sc);
                o1.x = f2bf(bf2f(a1.x)*sc); o1.y = f2bf(bf2f(a1.y)*sc);
                o1.z = f2bf(bf2f(a1.z)*sc); o1.w = f2bf(bf2f(a1.w)*sc);
                *(ushort4*)(dst + it * 8) = o0;
                *(ushort4*)(dst + it * 8 + 4) = o1;
            }
        }
        __syncthreads();
        f32x4 uacc[2];
#pragma unroll
        for (int nb = 0; nb < 2; ++nb) {
            f32x4 ci;
#pragma unroll
            for (int i = 0; i < 4; ++i) {
                const int t = t0 + quad * 4 + i;
                ci[i] = barr[t] * bf2f(vg[(size_t)(rowbase + t) * DVC + h * HVC + vs * 32 + nb * 16 + l15]);
            }
            uacc[nb] = ci;
        }
        for (int ks = 0; ks < 8; ++ks) {
            const bf8v af = *(const bf8v*)(buf + (t0 + l15) * 264 + ks * 32 + quad * 8);
#pragma unroll
            for (int nb = 0; nb < 2; ++nb) {
                const bf8v bf_ = *(const bf8v*)(&SbT[nb * 16 + l15][ks * 32 + quad * 8]);
                uacc[nb] = mfma16(af, bf_, uacc[nb]);
            }
        }
#pragma unroll
        for (int nb = 0; nb < 2; ++nb) {
            ushort4 p;
            p.x = f2bf(uacc[nb][0]); p.y = f2bf(uacc[nb][1]);
            p.z = f2bf(uacc[nb][2]); p.w = f2bf(uacc[nb][3]);
            *(ushort4*)(&tT[nb * 16 + l15][t0 + quad * 4]) = p;
        }
        __syncthreads();
        f32x4 vacc[2] = {(f32x4){0,0,0,0}, (f32x4){0,0,0,0}};
        for (int ks = 0; ks < 2; ++ks) {
            const bf8v am = *(const bf8v*)(Mg + (size_t)CI * 4096 + (t0 + l15) * 64 + ks * 32 + quad * 8);
#pragma unroll
            for (int nb = 0; nb < 2; ++nb) {
                const bf8v bu = *(const bf8v*)(&tT[nb * 16 + l15][ks * 32 + quad * 8]);
                vacc[nb] = mfma16(am, bu, vacc[nb]);
            }
        }
        {
            const float sc = gamt[srow];
            const u16* qrow = qg + (size_t)(rowbase + srow) * DKC + h * HKC + scq * 64;
            u16* dst = buf + srow * 264 + scq * 64;
#pragma unroll
            for (int it = 0; it < 8; ++it) {
                const ushort4 a0 = *(const ushort4*)(qrow + it * 8);
                const ushort4 a1 = *(const ushort4*)(qrow + it * 8 + 4);
                ushort4 o0, o1;
                o0.x = f2bf(bf2f(a0.x)*sc); o0.y = f2bf(bf2f(a0.y)*sc);
                o0.z = f2bf(bf2f(a0.z)*sc); o0.w = f2bf(bf2f(a0.w)*sc);
                o1.x = f2bf(bf2f(a1.x)*sc); o1.y = f2bf(bf2f(a1.y)*sc);
                o1.z = f2bf(bf2f(a1.z)*sc); o1.w = f2bf(bf2f(a1.w)*sc);
                *(ushort4*)(dst + it * 8) = o0;
                *(ushort4*)(dst + it * 8 + 4) = o1;
            }
        }
        __syncthreads();
#pragma unroll
        for (int nb = 0; nb < 2; ++nb) {
            ushort4 p;
            p.x = f2bf(vacc[nb][0]); p.y = f2bf(vacc[nb][1]);
            p.z = f2bf(vacc[nb][2]); p.w = f2bf(vacc[nb][3]);
            *(ushort4*)(&tT[nb * 16 + l15][t0 + quad * 4]) = p;
        }
        __syncthreads();
        f32x4 oacc[2] = {(f32x4){0,0,0,0}, (f32x4){0,0,0,0}};
        for (int ks = 0; ks < 2; ++ks) {
            const bf8v ap = *(const bf8v*)(Pg + (size_t)CI * 4096 + (t0 + l15) * 64 + ks * 32 + quad * 8);
#pragma unroll
            for (int nb = 0; nb < 2; ++nb) {
                const bf8v bv_ = *(const bf8v*)(&tT[nb * 16 + l15][ks * 32 + quad * 8]);
                oacc[nb] = mfma16(ap, bv_, oacc[nb]);
            }
        }
        for (int ks = 0; ks < 8; ++ks) {
            const bf8v af = *(const bf8v*)(buf + (t0 + l15) * 264 + ks * 32 + quad * 8);
#pragma unroll
            for (int nb = 0; nb < 2; ++nb) {
                const bf8v bs = *(const bf8v*)(&SbT[nb * 16 + l15][ks * 32 + quad * 8]);
                oacc[nb] = mfma16(af, bs, oacc[nb]);
            }
        }
#pragma unroll
        for (int nb = 0; nb < 2; ++nb)
#pragma unroll
            for (int i = 0; i < 4; ++i) {
                const int t = t0 + quad * 4 + i;
                og[((size_t)(b * 4 + h) * TT + c * 64 + t) * HVC + vs * 32 + nb * 16 + l15] = f2bf(oacc[nb][i]);
            }
        __syncthreads();
        {
            const float sc = gcdg[srow];
            const u16* krow = kg + (size_t)(rowbase + srow) * DKC + h * HKC + scq * 64;
#pragma unroll
            for (int it = 0; it < 8; ++it) {
                const ushort4 a0 = *(const ushort4*)(krow + it * 8);
                const ushort4 a1 = *(const ushort4*)(krow + it * 8 + 4);
                const int cbase = scq * 64 + it * 8;
                buf[(cbase + 0) * 72 + srow] = f2bf(bf2f(a0.x)*sc);
                buf[(cbase + 1) * 72 + srow] = f2bf(bf2f(a0.y)*sc);
                buf[(cbase + 2) * 72 + srow] = f2bf(bf2f(a0.z)*sc);
                buf[(cbase + 3) * 72 + srow] = f2bf(bf2f(a0.w)*sc);
                buf[(cbase + 4) * 72 + srow] = f2bf(bf2f(a1.x)*sc);
                buf[(cbase + 5) * 72 + srow] = f2bf(bf2f(a1.y)*sc);
                buf[(cbase + 6) * 72 + srow] = f2bf(bf2f(a1.z)*sc);
                buf[(cbase + 7) * 72 + srow] = f2bf(bf2f(a1.w)*sc);
            }
        }
        __syncthreads();
        const float gC = gCsh;
#pragma unroll
        for (int a = 0; a < 4; ++a) {
            const int r0 = (wave * 4 + a) * 16;
#pragma unroll
            for (int nb = 0; nb < 2; ++nb) {
                f32x4 acc = S[a][nb] * gC;
                for (int ks = 0; ks < 2; ++ks) {
                    const bf8v akt = *(const bf8v*)(buf + (r0 + l15) * 72 + ks * 32 + quad * 8);
                    const bf8v bv_ = *(const bf8v*)(&tT[nb * 16 + l15][ks * 32 + quad * 8]);
                    acc = mfma16(akt, bv_, acc);
                }
                S[a][nb] = acc;
                ushort4 p;
                p.x = f2bf(acc[0]); p.y = f2bf(acc[1]);
                p.z = f2bf(acc[2]); p.w = f2bf(acc[3]);
                *(ushort4*)(&SbT[nb * 16 + l15][r0 + quad * 4]) = p;
            }
        }
    }
}

// ---------------- RMSNorm + silu-gate; reads o (chunk layout), writes pg in place ----------------
__global__ __launch_bounds__(256) void gate_kernel(const u16* __restrict__ o,
                                                   u16* __restrict__ pg,
                                                   const float* __restrict__ norm_w) {
    const int row = blockIdx.x;
    const int b = row >> 11, t = row & 2047;
    const int tid = threadIdx.x;
    const int h = tid >> 6, lane = tid & 63;
    const size_t obase = ((size_t)(b * 4 + h) * TT + t) * HVC + lane * 4;
    const size_t pbase = (size_t)row * DVC + h * HVC + lane * 4;
    const ushort4 a4 = *(const ushort4*)&o[obase];
    const ushort4 b4 = *(const ushort4*)&o[obase + 256];
    float o1[4] = {bf2f(a4.x), bf2f(a4.y), bf2f(a4.z), bf2f(a4.w)};
    float o2[4] = {bf2f(b4.x), bf2f(b4.y), bf2f(b4.z), bf2f(b4.w)};
    float ss = 0.f;
#pragma unroll
    for (int j = 0; j < 4; ++j) ss += o1[j]*o1[j] + o2[j]*o2[j];
    for (int m = 32; m >= 1; m >>= 1) ss += __shfl_xor(ss, m, 64);
    const float rms = rsqrtf(ss * (1.0f / HVC) + 1e-5f);
    const float4 nw1 = *(const float4*)&norm_w[lane * 4];
    const float4 nw2 = *(const float4*)&norm_w[256 + lane * 4];
    const ushort4 g4a = *(const ushort4*)&pg[pbase];
    const ushort4 g4b = *(const ushort4*)&pg[pbase + 256];
    const float g1[4] = {bf2f(g4a.x), bf2f(g4a.y), bf2f(g4a.z), bf2f(g4a.w)};
    const float g2[4] = {bf2f(g4b.x), bf2f(g4b.y), bf2f(g4b.z), bf2f(g4b.w)};
    const float n1[4] = {nw1.x, nw1.y, nw1.z, nw1.w};
    const float n2[4] = {nw2.x, nw2.y, nw2.z, nw2.w};
    ushort4 r1, r2;
    u16* p1 = (u16*)&r1; u16* p2 = (u16*)&r2;
#pragma unroll
    for (int j = 0; j < 4; ++j) {
        p1[j] = f2bf(o1[j] * rms * n1[j] * g1[j] * sigmoidf_(g1[j]));
        p2[j] = f2bf(o2[j] * rms * n2[j] * g2[j] * sigmoidf_(g2[j]));
    }
    *(ushort4*)&pg[pbase] = r1;
    *(ushort4*)&pg[pbase + 256] = r2;
}

extern "C" void kernel_launch(void* const* d_in, const int* in_sizes, int n_in,
                              void* d_out, int out_size, void* d_ws, size_t ws_size,
                              hipStream_t stream) {
    const float* x       = (const float*)d_in[0];
    const float* ln_w    = (const float*)d_in[1];
    const float* ln_b    = (const float*)d_in[2];
    const float* Wq      = (const float*)d_in[3];
    const float* Wk      = (const float*)d_in[4];
    const float* Wv      = (const float*)d_in[5];
    const float* conv_q  = (const float*)d_in[6];
    const float* conv_k  = (const float*)d_in[7];
    const float* conv_v  = (const float*)d_in[8];
    const float* Wb      = (const float*)d_in[9];
    const float* Wa      = (const float*)d_in[10];
    const float* A_log   = (const float*)d_in[11];
    const float* dt_bias = (const float*)d_in[12];
    const float* Wg      = (const float*)d_in[13];
    const float* norm_w  = (const float*)d_in[14];
    const float* Wo      = (const float*)d_in[15];
    float* out = (float*)d_out;

    // Workspace layout: 124 MB peak (same as round 3)
    char* ws = (char*)d_ws;
    u16* normed = (u16*)(ws);                           // 16MB [0,16)
    u16* q      = (u16*)(ws + (16ull << 20));           // 16MB [16,32)
    u16* k      = (u16*)(ws + (32ull << 20));           // 16MB [32,48)
    u16* v      = (u16*)(ws + (48ull << 20));           // 32MB [48,80)
    u16* o      = (u16*)(ws + (80ull << 20));           // 32MB [80,112) chunk layout [B,H,T,HV]
    float* beta = (float*)(ws + (112ull << 20));              // 128KB
    float* gdec = (float*)(ws + (112ull << 20) + (128u<<10)); // 128KB
    float* gcg  = (float*)(ws + (112ull << 20) + (256u<<10)); // 128KB
    u16* halo   = (u16*)(ws + (113ull << 20));          // 3MB
    u16* Mg     = (u16*)(ws + (116ull << 20));          // 4MB
    u16* Pg     = (u16*)(ws + (120ull << 20));          // 4MB
    u16* pg     = q;                                    // 32MB (q+k region) after p2
    u16* WTe    = o;                                    // early weight-T scratch (o free until p2)
    u16* WgT    = Mg;                                   // Mg free after p2
    u16* WoT    = v;                                    // v free after p2

    ln_kernel<<<RTOT, 256, 0, stream>>>(x, ln_w, ln_b, normed);

    wconv_kernel<<<dim3(DD / 32, DKC / 32), 256, 0, stream>>>(Wq, WTe, DD, DKC);
    gemm_mfma<0><<<dim3(DKC / 128, RTOT / 128), 256, 0, stream>>>(normed, WTe, q, RTOT, DKC, DD, nullptr);
    wconv_kernel<<<dim3(DD / 32, DKC / 32), 256, 0, stream>>>(Wk, WTe, DD, DKC);
    gemm_mfma<0><<<dim3(DKC / 128, RTOT / 128), 256, 0, stream>>>(normed, WTe, k, RTOT, DKC, DD, nullptr);
    wconv_kernel<<<dim3(DD / 32, DVC / 32), 256, 0, stream>>>(Wv, WTe, DD, DVC);
    gemm_mfma<0><<<dim3(DVC / 128, RTOT / 128), 256, 0, stream>>>(normed, WTe, v, RTOT, DVC, DD, nullptr);
    smallproj_kernel<<<RTOT, 256, 0, stream>>>(x, ln_w, ln_b, Wb, Wa, A_log, dt_bias, beta, gdec);

    halo_save<<<RTOT / TILE_CV, 256, 0, stream>>>(q, halo, DKC);
    conv_inplace<<<dim3(1, RTOT / TILE_CV), 256, 0, stream>>>(q, conv_q, halo, DKC);
    halo_save<<<RTOT / TILE_CV, 256, 0, stream>>>(k, halo, DKC);
    conv_inplace<<<dim3(1, RTOT / TILE_CV), 256, 0, stream>>>(k, conv_k, halo, DKC);
    halo_save<<<RTOT / TILE_CV, 256, 0, stream>>>(v, halo, DVC);
    conv_inplace<<<dim3(2, RTOT / TILE_CV), 256, 0, stream>>>(v, conv_v, halo, DVC);

    normqk_kernel<<<RTOT, 256, 0, stream>>>(q, k);

    p1a_kernel<<<BB * HH * NC, 256, 0, stream>>>(q, k, gdec, beta, Mg, Pg, gcg);
    p2_kernel<<<BB * HH * (HVC / 32), 256, 0, stream>>>(q, k, v, beta, gcg, Mg, Pg, o);

    // q,k dead -> pg; Mg dead -> WgT; v dead -> WoT
    wconv_kernel<<<dim3(DD / 32, DVC / 32), 256, 0, stream>>>(Wg, WgT, DD, DVC);
    gemm_mfma<0><<<dim3(DVC / 128, RTOT / 128), 256, 0, stream>>>(normed, WgT, pg, RTOT, DVC, DD, nullptr);

    gate_kernel<<<RTOT, 256, 0, stream>>>(o, pg, norm_w);

    wconv_kernel<<<dim3(DVC / 32, DD / 32), 256, 0, stream>>>(Wo, WoT, DVC, DD);
    gemm_mfma<1><<<dim3(DD / 128, RTOT / 128), 256, 0, stream>>>(pg, WoT, out, RTOT, DD, DVC, x);
}